// Round 1
// baseline (6071.521 us; speedup 1.0000x reference)
//
#include <hip/hip_runtime.h>
#include <math.h>

#define NHEADS 16
#define HD 64

// C[M,N] = A[M,K] @ B[N,K]^T + bias[N]   (A,B row-major, K contiguous in both)
template<int BM, int BN, int BK, int TM, int TN>
__global__ void gemm_nt_bias(const float* __restrict__ A, const float* __restrict__ B,
                             const float* __restrict__ bias, float* __restrict__ C,
                             int M, int N, int K) {
    __shared__ float As[BM][BK + 1];
    __shared__ float Bs[BN][BK + 1];
    const int tid = threadIdx.x;
    const int brow = blockIdx.y * BM;
    const int bcol = blockIdx.x * BN;
    constexpr int THREADS_X = BN / TN;  // 16
    const int tx = tid % THREADS_X;
    const int ty = tid / THREADS_X;
    float acc[TM][TN] = {};
    for (int k0 = 0; k0 < K; k0 += BK) {
        for (int i = tid; i < BM * BK; i += blockDim.x) {
            int r = i / BK, c = i % BK;
            As[r][c] = A[(size_t)(brow + r) * K + k0 + c];
        }
        for (int i = tid; i < BN * BK; i += blockDim.x) {
            int r = i / BK, c = i % BK;
            Bs[r][c] = B[(size_t)(bcol + r) * K + k0 + c];
        }
        __syncthreads();
        #pragma unroll
        for (int kk = 0; kk < BK; ++kk) {
            float a[TM], b[TN];
            #pragma unroll
            for (int i = 0; i < TM; ++i) a[i] = As[ty * TM + i][kk];
            #pragma unroll
            for (int j = 0; j < TN; ++j) b[j] = Bs[tx * TN + j][kk];
            #pragma unroll
            for (int i = 0; i < TM; ++i)
                #pragma unroll
                for (int j = 0; j < TN; ++j)
                    acc[i][j] += a[i] * b[j];
        }
        __syncthreads();
    }
    #pragma unroll
    for (int i = 0; i < TM; ++i)
        #pragma unroll
        for (int j = 0; j < TN; ++j) {
            int r = brow + ty * TM + i, c = bcol + tx * TN + j;
            C[(size_t)r * N + c] = acc[i][j] + bias[c];
        }
}

// One thread per (b, h, query-row). Online softmax over all S keys.
// qkv layout: [B*S, 3*D] with head-h q at col h*192, k at h*192+64, v at h*192+128.
__global__ void attn_kernel(const float* __restrict__ qkv, float* __restrict__ vals,
                            int B, int S) {
    const int gid = blockIdx.x * blockDim.x + threadIdx.x;
    const int s = gid % S;
    const int bh = gid / S;
    const int h = bh % NHEADS;
    const int b = bh / NHEADS;
    const size_t rowstride = 3 * 1024;
    const float scale = 0.125f;  // 1/sqrt(64)

    const float* qrow = qkv + ((size_t)(b * S + s)) * rowstride + h * 3 * HD;
    float q[HD];
    #pragma unroll
    for (int d = 0; d < HD; ++d) q[d] = qrow[d] * scale;

    float m = -INFINITY, l = 0.f;
    float acc[HD] = {};
    const float* kbase = qkv + ((size_t)(b * S)) * rowstride + h * 3 * HD + HD;
    for (int j = 0; j < S; ++j) {
        const float* krow = kbase + (size_t)j * rowstride;
        float dot = 0.f;
        #pragma unroll
        for (int d = 0; d < HD; ++d) dot += q[d] * krow[d];
        float mnew = fmaxf(m, dot);
        float corr = __expf(m - mnew);
        float p = __expf(dot - mnew);
        l = l * corr + p;
        const float* vrow = krow + HD;
        #pragma unroll
        for (int d = 0; d < HD; ++d) acc[d] = acc[d] * corr + p * vrow[d];
        m = mnew;
    }
    float inv = 1.f / l;
    float* outrow = vals + ((size_t)(b * S + s)) * 1024 + h * HD;
    #pragma unroll
    for (int d = 0; d < HD; ++d) outrow[d] = acc[d] * inv;
}

extern "C" void kernel_launch(void* const* d_in, const int* in_sizes, int n_in,
                              void* d_out, int out_size, void* d_ws, size_t ws_size,
                              hipStream_t stream) {
    const float* x     = (const float*)d_in[0];
    const float* w_qkv = (const float*)d_in[1];
    const float* b_qkv = (const float*)d_in[2];
    const float* w_o   = (const float*)d_in[3];
    const float* b_o   = (const float*)d_in[4];
    float* out = (float*)d_out;

    const int B = 2, S = 2048, D = 1024;
    const int M = B * S;          // 4096
    const int N1 = 3 * D;         // 3072

    float* qkv  = (float*)d_ws;                  // [M, 3D]  50.3 MB
    float* vals = qkv + (size_t)M * N1;          // [M, D]   16.8 MB

    // 1) qkv = x @ w_qkv^T + b_qkv
    dim3 g1(N1 / 64, M / 64);
    gemm_nt_bias<64, 64, 16, 4, 4><<<g1, 256, 0, stream>>>(x, w_qkv, b_qkv, qkv, M, N1, D);

    // 2) attention
    int total = B * NHEADS * S;   // 65536 threads
    attn_kernel<<<total / 256, 256, 0, stream>>>(qkv, vals, B, S);

    // 3) out = vals @ w_o^T + b_o
    dim3 g3(D / 64, M / 64);
    gemm_nt_bias<64, 64, 16, 4, 4><<<g3, 256, 0, stream>>>(vals, w_o, b_o, out, M, D, D);
}

// Round 2
// 1336.106 us; speedup vs baseline: 4.5442x; 4.5442x over previous
//
#include <hip/hip_runtime.h>
#include <math.h>

#define NHEADS 16
#define HD 64
#define PQ 68  // LDS row stride (floats): 16B-aligned, tolerable bank pattern

// C[M,N] = A[M,K] @ B[N,K]^T + bias[N]   (A,B row-major, K contiguous in both)
template<int BM, int BN, int BK, int TM, int TN>
__global__ void gemm_nt_bias(const float* __restrict__ A, const float* __restrict__ B,
                             const float* __restrict__ bias, float* __restrict__ C,
                             int M, int N, int K) {
    __shared__ float As[BM][BK + 1];
    __shared__ float Bs[BN][BK + 1];
    const int tid = threadIdx.x;
    const int brow = blockIdx.y * BM;
    const int bcol = blockIdx.x * BN;
    constexpr int THREADS_X = BN / TN;  // 16
    const int tx = tid % THREADS_X;
    const int ty = tid / THREADS_X;
    float acc[TM][TN] = {};
    for (int k0 = 0; k0 < K; k0 += BK) {
        for (int i = tid; i < BM * BK; i += blockDim.x) {
            int r = i / BK, c = i % BK;
            As[r][c] = A[(size_t)(brow + r) * K + k0 + c];
        }
        for (int i = tid; i < BN * BK; i += blockDim.x) {
            int r = i / BK, c = i % BK;
            Bs[r][c] = B[(size_t)(bcol + r) * K + k0 + c];
        }
        __syncthreads();
        #pragma unroll
        for (int kk = 0; kk < BK; ++kk) {
            float a[TM], b[TN];
            #pragma unroll
            for (int i = 0; i < TM; ++i) a[i] = As[ty * TM + i][kk];
            #pragma unroll
            for (int j = 0; j < TN; ++j) b[j] = Bs[tx * TN + j][kk];
            #pragma unroll
            for (int i = 0; i < TM; ++i)
                #pragma unroll
                for (int j = 0; j < TN; ++j)
                    acc[i][j] += a[i] * b[j];
        }
        __syncthreads();
    }
    #pragma unroll
    for (int i = 0; i < TM; ++i)
        #pragma unroll
        for (int j = 0; j < TN; ++j) {
            int r = brow + ty * TM + i, c = bcol + tx * TN + j;
            C[(size_t)r * N + c] = acc[i][j] + bias[c];
        }
}

// Tiled fp32 flash attention.
// Grid: (S/64, B*H). Block: 256 threads = 16x16, each owns 4x4 of S-tile and 4x4 of O.
// qkv layout: [B*S, 3072]; head h: q at h*192, k at h*192+64, v at h*192+128.
__global__ __launch_bounds__(256, 2) void flash_attn(const float* __restrict__ qkv,
                                                     float* __restrict__ vals,
                                                     int B, int S) {
    __shared__ float Qs[64][PQ];   // [qrow][d], pre-scaled
    __shared__ float KsT[64][PQ];  // [d][krow]  (transposed)
    __shared__ float Vs[64][PQ];   // [krow][d]
    __shared__ float Ps[64][PQ];   // [qrow][krow]
    const int tid = threadIdx.x;
    const int tx = tid & 15, ty = tid >> 4;
    const int bh = blockIdx.y;
    const int h = bh & (NHEADS - 1), b = bh >> 4;
    const int q0 = blockIdx.x * 64;
    const size_t rs = 3072;
    const float scale = 0.125f;  // 1/sqrt(64)

    // ---- load Q tile (pre-scaled) ----
    {
        const float* qb = qkv + ((size_t)(b * S + q0)) * rs + h * 3 * HD;
        for (int r = ty; r < 64; r += 16) {
            float4 v4 = *(const float4*)(qb + (size_t)r * rs + tx * 4);
            v4.x *= scale; v4.y *= scale; v4.z *= scale; v4.w *= scale;
            *(float4*)&Qs[r][tx * 4] = v4;
        }
    }

    float m[4], l[4], acc[4][4];
    #pragma unroll
    for (int i = 0; i < 4; ++i) {
        m[i] = -INFINITY; l[i] = 0.f;
        #pragma unroll
        for (int j = 0; j < 4; ++j) acc[i][j] = 0.f;
    }

    const float* kb = qkv + ((size_t)b * S) * rs + h * 3 * HD + HD;
    const float* vb = kb + HD;

    const int NT = S / 64;
    for (int kt = 0; kt < NT; ++kt) {
        __syncthreads();  // previous PV done before overwriting Ks/Vs
        // ---- load K (transposed) and V tiles ----
        for (int r = ty; r < 64; r += 16) {
            size_t off = ((size_t)(kt * 64 + r)) * rs + tx * 4;
            float4 k4 = *(const float4*)(kb + off);
            KsT[tx * 4 + 0][r] = k4.x;
            KsT[tx * 4 + 1][r] = k4.y;
            KsT[tx * 4 + 2][r] = k4.z;
            KsT[tx * 4 + 3][r] = k4.w;
            *(float4*)&Vs[r][tx * 4] = *(const float4*)(vb + off);
        }
        __syncthreads();

        // ---- S = Qs @ K^T  (4x4 per thread) ----
        float s[4][4] = {};
        #pragma unroll 4
        for (int kk = 0; kk < HD; kk += 4) {
            float4 a4[4], b4[4];
            #pragma unroll
            for (int i = 0; i < 4; ++i) a4[i] = *(const float4*)&Qs[ty * 4 + i][kk];
            #pragma unroll
            for (int c = 0; c < 4; ++c) b4[c] = *(const float4*)&KsT[kk + c][tx * 4];
            #pragma unroll
            for (int i = 0; i < 4; ++i) {
                const float ac[4] = {a4[i].x, a4[i].y, a4[i].z, a4[i].w};
                #pragma unroll
                for (int c = 0; c < 4; ++c) {
                    s[i][0] += ac[c] * b4[c].x;
                    s[i][1] += ac[c] * b4[c].y;
                    s[i][2] += ac[c] * b4[c].z;
                    s[i][3] += ac[c] * b4[c].w;
                }
            }
        }

        // ---- online softmax (per row; redundant across the 16 tx lanes) ----
        float corr_r[4];
        #pragma unroll
        for (int i = 0; i < 4; ++i) {
            float rmax = fmaxf(fmaxf(s[i][0], s[i][1]), fmaxf(s[i][2], s[i][3]));
            #pragma unroll
            for (int o = 1; o < 16; o <<= 1) rmax = fmaxf(rmax, __shfl_xor(rmax, o, 64));
            float mnew = fmaxf(m[i], rmax);
            float corr = __expf(m[i] - mnew);
            float p0 = __expf(s[i][0] - mnew);
            float p1 = __expf(s[i][1] - mnew);
            float p2 = __expf(s[i][2] - mnew);
            float p3 = __expf(s[i][3] - mnew);
            float rsum = (p0 + p1) + (p2 + p3);
            #pragma unroll
            for (int o = 1; o < 16; o <<= 1) rsum += __shfl_xor(rsum, o, 64);
            l[i] = l[i] * corr + rsum;
            m[i] = mnew;
            corr_r[i] = corr;
            *(float4*)&Ps[ty * 4 + i][tx * 4] = make_float4(p0, p1, p2, p3);
        }
        __syncthreads();

        // ---- O = O*corr + P @ V  (4x4 per thread: rows ty*4.., dims tx*4..) ----
        #pragma unroll
        for (int i = 0; i < 4; ++i)
            #pragma unroll
            for (int d = 0; d < 4; ++d) acc[i][d] *= corr_r[i];
        #pragma unroll 4
        for (int jj = 0; jj < 64; jj += 4) {
            float4 pr[4], vr[4];
            #pragma unroll
            for (int i = 0; i < 4; ++i) pr[i] = *(const float4*)&Ps[ty * 4 + i][jj];
            #pragma unroll
            for (int c = 0; c < 4; ++c) vr[c] = *(const float4*)&Vs[jj + c][tx * 4];
            #pragma unroll
            for (int i = 0; i < 4; ++i) {
                const float pc[4] = {pr[i].x, pr[i].y, pr[i].z, pr[i].w};
                #pragma unroll
                for (int c = 0; c < 4; ++c) {
                    acc[i][0] += pc[c] * vr[c].x;
                    acc[i][1] += pc[c] * vr[c].y;
                    acc[i][2] += pc[c] * vr[c].z;
                    acc[i][3] += pc[c] * vr[c].w;
                }
            }
        }
    }

    // ---- epilogue: vals[b, q0+row, h*64 + d] = acc/l ----
    float* ob = vals + ((size_t)(b * S + q0)) * 1024 + h * HD;
    #pragma unroll
    for (int i = 0; i < 4; ++i) {
        float inv = 1.f / l[i];
        float4 o;
        o.x = acc[i][0] * inv; o.y = acc[i][1] * inv;
        o.z = acc[i][2] * inv; o.w = acc[i][3] * inv;
        *(float4*)(ob + (size_t)(ty * 4 + i) * 1024 + tx * 4) = o;
    }
}

extern "C" void kernel_launch(void* const* d_in, const int* in_sizes, int n_in,
                              void* d_out, int out_size, void* d_ws, size_t ws_size,
                              hipStream_t stream) {
    const float* x     = (const float*)d_in[0];
    const float* w_qkv = (const float*)d_in[1];
    const float* b_qkv = (const float*)d_in[2];
    const float* w_o   = (const float*)d_in[3];
    const float* b_o   = (const float*)d_in[4];
    float* out = (float*)d_out;

    const int B = 2, S = 2048, D = 1024;
    const int M = B * S;          // 4096
    const int N1 = 3 * D;         // 3072

    float* qkv  = (float*)d_ws;                  // [M, 3D]
    float* vals = qkv + (size_t)M * N1;          // [M, D]

    // 1) qkv = x @ w_qkv^T + b_qkv
    dim3 g1(N1 / 64, M / 64);
    gemm_nt_bias<64, 64, 16, 4, 4><<<g1, 256, 0, stream>>>(x, w_qkv, b_qkv, qkv, M, N1, D);

    // 2) flash attention
    dim3 g2(S / 64, B * NHEADS);
    flash_attn<<<g2, 256, 0, stream>>>(qkv, vals, B, S);

    // 3) out = vals @ w_o^T + b_o
    dim3 g3(D / 64, M / 64);
    gemm_nt_bias<64, 64, 16, 4, 4><<<g3, 256, 0, stream>>>(vals, w_o, b_o, out, M, D, D);
}

// Round 3
// 756.399 us; speedup vs baseline: 8.0269x; 1.7664x over previous
//
#include <hip/hip_runtime.h>
#include <math.h>

#define NHEADS 16
#define HD 64
#define PQ 68

typedef __attribute__((ext_vector_type(8))) short short8;
typedef __attribute__((ext_vector_type(4))) float f32x4;

__device__ inline unsigned short f2bf(float f) {
    unsigned int u = __float_as_uint(f);
    u += 0x7fff + ((u >> 16) & 1);
    return (unsigned short)(u >> 16);
}
__device__ inline float bf2f(unsigned short h) {
    return __uint_as_float(((unsigned int)h) << 16);
}

__device__ inline void load_lds16(const void* g, void* l) {
    __builtin_amdgcn_global_load_lds(
        (const __attribute__((address_space(1))) unsigned int*)g,
        (__attribute__((address_space(3))) unsigned int*)l, 16, 0, 0);
}

// fp32 -> (hi bf16, lo bf16), elementwise, 4/thread
__global__ void split_kernel(const float* __restrict__ in, unsigned short* __restrict__ hi,
                             unsigned short* __restrict__ lo, int n) {
    int i = (blockIdx.x * blockDim.x + threadIdx.x) * 4;
    if (i >= n) return;
    float4 v = *(const float4*)(in + i);
    ushort4 h, l;
    h.x = f2bf(v.x); l.x = f2bf(v.x - bf2f(h.x));
    h.y = f2bf(v.y); l.y = f2bf(v.y - bf2f(h.y));
    h.z = f2bf(v.z); l.z = f2bf(v.z - bf2f(h.z));
    h.w = f2bf(v.w); l.w = f2bf(v.w - bf2f(h.w));
    *(ushort4*)(hi + i) = h;
    *(ushort4*)(lo + i) = l;
}

// C[M,N] = (Ah+Al)[M,K] @ (Bh+Bl)[N,K]^T + bias[N], split-bf16 MFMA (drop Al*Bl).
// 128x128 tile, BK=32, 256 threads = 4 waves (2x2), each wave 64x64 = 4x4 frags of 16x16.
__global__ __launch_bounds__(256, 2) void gemm_split(
    const unsigned short* __restrict__ Ah, const unsigned short* __restrict__ Al,
    const unsigned short* __restrict__ Bh, const unsigned short* __restrict__ Bl,
    const float* __restrict__ bias, float* __restrict__ C,
    int M, int N, int K) {
    // LDS: Ah[128][32] @0, Al @8192, Bh @16384, Bl @24576 (bf16, row-major, 64B rows,
    // 16B slots XOR-swizzled: slot' = slot ^ ((row>>1)&3))
    __shared__ __align__(1024) unsigned char smem[32768];
    const int tid = threadIdx.x;
    const int l = tid & 63, w = tid >> 6;
    const int wr = w >> 1, wc = w & 1;
    const int m0 = blockIdx.y * 128, n0 = blockIdx.x * 128;

    // staging: thread t covers LDS row (t>>2), slot (t&3); source chunk pre-swizzled
    const int srow = tid >> 2;
    const int schunk = (tid & 3) ^ ((srow >> 1) & 3);
    const size_t gA0 = (size_t)(m0 + srow) * K + schunk * 8;
    const size_t gA1 = gA0 + (size_t)64 * K;
    const size_t gB0 = (size_t)(n0 + srow) * K + schunk * 8;
    const size_t gB1 = gB0 + (size_t)64 * K;
    unsigned char* ldsW = smem + w * 1024;  // wave-uniform dest base

    // fragment read offsets (lane l reads row (l&15)+16m, k-chunk l>>4)
    const int col16 = l & 15, kc = l >> 4;
    const int ra0 = wr * 64 + col16;
    const int offA = ra0 * 64 + ((kc ^ ((ra0 >> 1) & 3)) * 16);
    const int rb0 = wc * 64 + col16;
    const int offB = rb0 * 64 + ((kc ^ ((rb0 >> 1) & 3)) * 16);

    f32x4 acc[4][4] = {};

    for (int k0 = 0; k0 < K; k0 += 32) {
        load_lds16(Ah + gA0 + k0, ldsW + 0);
        load_lds16(Ah + gA1 + k0, ldsW + 4096);
        load_lds16(Al + gA0 + k0, ldsW + 8192);
        load_lds16(Al + gA1 + k0, ldsW + 12288);
        load_lds16(Bh + gB0 + k0, ldsW + 16384);
        load_lds16(Bh + gB1 + k0, ldsW + 20480);
        load_lds16(Bl + gB0 + k0, ldsW + 24576);
        load_lds16(Bl + gB1 + k0, ldsW + 28672);
        __syncthreads();

        short8 ah[4], al[4], bh[4], bl[4];
        #pragma unroll
        for (int m = 0; m < 4; ++m) {
            ah[m] = *(const short8*)(smem + 0    + offA + m * 1024);
            al[m] = *(const short8*)(smem + 8192 + offA + m * 1024);
        }
        #pragma unroll
        for (int n = 0; n < 4; ++n) {
            bh[n] = *(const short8*)(smem + 16384 + offB + n * 1024);
            bl[n] = *(const short8*)(smem + 24576 + offB + n * 1024);
        }
        #pragma unroll
        for (int m = 0; m < 4; ++m)
            #pragma unroll
            for (int n = 0; n < 4; ++n) {
                acc[m][n] = __builtin_amdgcn_mfma_f32_16x16x32_bf16(ah[m], bh[n], acc[m][n], 0, 0, 0);
                acc[m][n] = __builtin_amdgcn_mfma_f32_16x16x32_bf16(ah[m], bl[n], acc[m][n], 0, 0, 0);
                acc[m][n] = __builtin_amdgcn_mfma_f32_16x16x32_bf16(al[m], bh[n], acc[m][n], 0, 0, 0);
            }
        __syncthreads();
    }

    // epilogue: C/D layout col=lane&15, row=(lane>>4)*4+j
    const int rowb = m0 + wr * 64 + (l >> 4) * 4;
    const int colb = n0 + wc * 64 + col16;
    float bv[4];
    #pragma unroll
    for (int n = 0; n < 4; ++n) bv[n] = bias[colb + n * 16];
    #pragma unroll
    for (int m = 0; m < 4; ++m)
        #pragma unroll
        for (int j = 0; j < 4; ++j) {
            float* crow = C + (size_t)(rowb + m * 16 + j) * N + colb;
            #pragma unroll
            for (int n = 0; n < 4; ++n) crow[n * 16] = acc[m][n][j] + bv[n];
        }
}

// Tiled fp32 flash attention (unchanged from round 1).
__global__ __launch_bounds__(256, 2) void flash_attn(const float* __restrict__ qkv,
                                                     float* __restrict__ vals,
                                                     int B, int S) {
    __shared__ float Qs[64][PQ];
    __shared__ float KsT[64][PQ];
    __shared__ float Vs[64][PQ];
    __shared__ float Ps[64][PQ];
    const int tid = threadIdx.x;
    const int tx = tid & 15, ty = tid >> 4;
    const int bh = blockIdx.y;
    const int h = bh & (NHEADS - 1), b = bh >> 4;
    const int q0 = blockIdx.x * 64;
    const size_t rs = 3072;
    const float scale = 0.125f;

    {
        const float* qb = qkv + ((size_t)(b * S + q0)) * rs + h * 3 * HD;
        for (int r = ty; r < 64; r += 16) {
            float4 v4 = *(const float4*)(qb + (size_t)r * rs + tx * 4);
            v4.x *= scale; v4.y *= scale; v4.z *= scale; v4.w *= scale;
            *(float4*)&Qs[r][tx * 4] = v4;
        }
    }

    float m[4], l[4], acc[4][4];
    #pragma unroll
    for (int i = 0; i < 4; ++i) {
        m[i] = -INFINITY; l[i] = 0.f;
        #pragma unroll
        for (int j = 0; j < 4; ++j) acc[i][j] = 0.f;
    }

    const float* kb = qkv + ((size_t)b * S) * rs + h * 3 * HD + HD;
    const float* vb = kb + HD;

    const int NT = S / 64;
    for (int kt = 0; kt < NT; ++kt) {
        __syncthreads();
        for (int r = ty; r < 64; r += 16) {
            size_t off = ((size_t)(kt * 64 + r)) * rs + tx * 4;
            float4 k4 = *(const float4*)(kb + off);
            KsT[tx * 4 + 0][r] = k4.x;
            KsT[tx * 4 + 1][r] = k4.y;
            KsT[tx * 4 + 2][r] = k4.z;
            KsT[tx * 4 + 3][r] = k4.w;
            *(float4*)&Vs[r][tx * 4] = *(const float4*)(vb + off);
        }
        __syncthreads();

        float s[4][4] = {};
        #pragma unroll 4
        for (int kk = 0; kk < HD; kk += 4) {
            float4 a4[4], b4[4];
            #pragma unroll
            for (int i = 0; i < 4; ++i) a4[i] = *(const float4*)&Qs[ty * 4 + i][kk];
            #pragma unroll
            for (int c = 0; c < 4; ++c) b4[c] = *(const float4*)&KsT[kk + c][tx * 4];
            #pragma unroll
            for (int i = 0; i < 4; ++i) {
                const float ac[4] = {a4[i].x, a4[i].y, a4[i].z, a4[i].w};
                #pragma unroll
                for (int c = 0; c < 4; ++c) {
                    s[i][0] += ac[c] * b4[c].x;
                    s[i][1] += ac[c] * b4[c].y;
                    s[i][2] += ac[c] * b4[c].z;
                    s[i][3] += ac[c] * b4[c].w;
                }
            }
        }

        float corr_r[4];
        #pragma unroll
        for (int i = 0; i < 4; ++i) {
            float rmax = fmaxf(fmaxf(s[i][0], s[i][1]), fmaxf(s[i][2], s[i][3]));
            #pragma unroll
            for (int o = 1; o < 16; o <<= 1) rmax = fmaxf(rmax, __shfl_xor(rmax, o, 64));
            float mnew = fmaxf(m[i], rmax);
            float corr = __expf(m[i] - mnew);
            float p0 = __expf(s[i][0] - mnew);
            float p1 = __expf(s[i][1] - mnew);
            float p2 = __expf(s[i][2] - mnew);
            float p3 = __expf(s[i][3] - mnew);
            float rsum = (p0 + p1) + (p2 + p3);
            #pragma unroll
            for (int o = 1; o < 16; o <<= 1) rsum += __shfl_xor(rsum, o, 64);
            l[i] = l[i] * corr + rsum;
            m[i] = mnew;
            corr_r[i] = corr;
            *(float4*)&Ps[ty * 4 + i][tx * 4] = make_float4(p0, p1, p2, p3);
        }
        __syncthreads();

        #pragma unroll
        for (int i = 0; i < 4; ++i)
            #pragma unroll
            for (int d = 0; d < 4; ++d) acc[i][d] *= corr_r[i];
        #pragma unroll 4
        for (int jj = 0; jj < 64; jj += 4) {
            float4 pr[4], vr[4];
            #pragma unroll
            for (int i = 0; i < 4; ++i) pr[i] = *(const float4*)&Ps[ty * 4 + i][jj];
            #pragma unroll
            for (int c = 0; c < 4; ++c) vr[c] = *(const float4*)&Vs[jj + c][tx * 4];
            #pragma unroll
            for (int i = 0; i < 4; ++i) {
                const float pc[4] = {pr[i].x, pr[i].y, pr[i].z, pr[i].w};
                #pragma unroll
                for (int c = 0; c < 4; ++c) {
                    acc[i][0] += pc[c] * vr[c].x;
                    acc[i][1] += pc[c] * vr[c].y;
                    acc[i][2] += pc[c] * vr[c].z;
                    acc[i][3] += pc[c] * vr[c].w;
                }
            }
        }
    }

    float* ob = vals + ((size_t)(b * S + q0)) * 1024 + h * HD;
    #pragma unroll
    for (int i = 0; i < 4; ++i) {
        float inv = 1.f / l[i];
        float4 o;
        o.x = acc[i][0] * inv; o.y = acc[i][1] * inv;
        o.z = acc[i][2] * inv; o.w = acc[i][3] * inv;
        *(float4*)(ob + (size_t)(ty * 4 + i) * 1024 + tx * 4) = o;
    }
}

extern "C" void kernel_launch(void* const* d_in, const int* in_sizes, int n_in,
                              void* d_out, int out_size, void* d_ws, size_t ws_size,
                              hipStream_t stream) {
    const float* x     = (const float*)d_in[0];
    const float* w_qkv = (const float*)d_in[1];
    const float* b_qkv = (const float*)d_in[2];
    const float* w_o   = (const float*)d_in[3];
    const float* b_o   = (const float*)d_in[4];
    float* out = (float*)d_out;

    const int B = 2, S = 2048, D = 1024;
    const int M = B * S;          // 4096
    const int N1 = 3 * D;         // 3072

    float* qkv  = (float*)d_ws;                       // [4096,3072] f32
    float* vals = qkv + (size_t)M * N1;               // [4096,1024] f32
    unsigned short* xh  = (unsigned short*)(vals + (size_t)M * D);
    unsigned short* xl  = xh  + (size_t)M * D;        // x split [4096,1024]
    unsigned short* wqh = xl  + (size_t)M * D;        // w_qkv split [3072,1024]
    unsigned short* wql = wqh + (size_t)N1 * D;
    unsigned short* woh = wql + (size_t)N1 * D;       // w_o split [1024,1024]
    unsigned short* wol = woh + (size_t)D * D;
    // reuse x-split space for vals-split after GEMM1
    unsigned short* vh = xh;
    unsigned short* vl = xl;

    split_kernel<<<(M * D) / 1024, 256, 0, stream>>>(x, xh, xl, M * D);
    split_kernel<<<(N1 * D) / 1024, 256, 0, stream>>>(w_qkv, wqh, wql, N1 * D);
    split_kernel<<<(D * D) / 1024, 256, 0, stream>>>(w_o, woh, wol, D * D);

    // 1) qkv = x @ w_qkv^T + b_qkv
    gemm_split<<<dim3(N1 / 128, M / 128), 256, 0, stream>>>(xh, xl, wqh, wql, b_qkv, qkv, M, N1, D);

    // 2) flash attention
    flash_attn<<<dim3(S / 64, B * NHEADS), 256, 0, stream>>>(qkv, vals, B, S);

    // 3) out = vals @ w_o^T + b_o
    split_kernel<<<(M * D) / 1024, 256, 0, stream>>>(vals, vh, vl, M * D);
    gemm_split<<<dim3(D / 128, M / 128), 256, 0, stream>>>(vh, vl, woh, wol, b_o, out, M, D, D);
}

// Round 4
// 232.829 us; speedup vs baseline: 26.0772x; 3.2487x over previous
//
#include <hip/hip_runtime.h>
#include <math.h>

#define NHEADS 16
#define HD 64

typedef __attribute__((ext_vector_type(8))) short short8;
typedef __attribute__((ext_vector_type(4))) float f32x4;
typedef __attribute__((ext_vector_type(8))) unsigned short ushort8;

__device__ inline unsigned short f2bf(float f) {
    unsigned int u = __float_as_uint(f);
    u += 0x7fff + ((u >> 16) & 1);
    return (unsigned short)(u >> 16);
}
__device__ inline float bf2f(unsigned short h) {
    return __uint_as_float(((unsigned int)h) << 16);
}
__device__ inline unsigned int pack2bf(float lo, float hi) {
    return (unsigned int)f2bf(lo) | ((unsigned int)f2bf(hi) << 16);
}
__device__ inline void load_lds16(const void* g, void* l) {
    __builtin_amdgcn_global_load_lds(
        (const __attribute__((address_space(1))) unsigned int*)g,
        (__attribute__((address_space(3))) unsigned int*)l, 16, 0, 0);
}

// fp32 -> (hi bf16, lo bf16), elementwise, 4/thread
__global__ void split_kernel(const float* __restrict__ in, unsigned short* __restrict__ hi,
                             unsigned short* __restrict__ lo, int n) {
    int i = (blockIdx.x * blockDim.x + threadIdx.x) * 4;
    if (i >= n) return;
    float4 v = *(const float4*)(in + i);
    ushort4 h, l;
    h.x = f2bf(v.x); l.x = f2bf(v.x - bf2f(h.x));
    h.y = f2bf(v.y); l.y = f2bf(v.y - bf2f(h.y));
    h.z = f2bf(v.z); l.z = f2bf(v.z - bf2f(h.z));
    h.w = f2bf(v.w); l.w = f2bf(v.w - bf2f(h.w));
    *(ushort4*)(hi + i) = h;
    *(ushort4*)(lo + i) = l;
}

// C[M,N] = (Ah+Al)[M,K] @ (Bh+Bl)[N,K]^T + bias[N], split-bf16 MFMA (drop Al*Bl).
__global__ __launch_bounds__(256, 2) void gemm_split(
    const unsigned short* __restrict__ Ah, const unsigned short* __restrict__ Al,
    const unsigned short* __restrict__ Bh, const unsigned short* __restrict__ Bl,
    const float* __restrict__ bias, float* __restrict__ C,
    int M, int N, int K) {
    __shared__ __align__(1024) unsigned char smem[32768];
    const int tid = threadIdx.x;
    const int l = tid & 63, w = tid >> 6;
    const int wr = w >> 1, wc = w & 1;
    const int m0 = blockIdx.y * 128, n0 = blockIdx.x * 128;

    const int srow = tid >> 2;
    const int schunk = (tid & 3) ^ ((srow >> 1) & 3);
    const size_t gA0 = (size_t)(m0 + srow) * K + schunk * 8;
    const size_t gA1 = gA0 + (size_t)64 * K;
    const size_t gB0 = (size_t)(n0 + srow) * K + schunk * 8;
    const size_t gB1 = gB0 + (size_t)64 * K;
    unsigned char* ldsW = smem + w * 1024;

    const int col16 = l & 15, kc = l >> 4;
    const int ra0 = wr * 64 + col16;
    const int offA = ra0 * 64 + ((kc ^ ((ra0 >> 1) & 3)) * 16);
    const int rb0 = wc * 64 + col16;
    const int offB = rb0 * 64 + ((kc ^ ((rb0 >> 1) & 3)) * 16);

    f32x4 acc[4][4] = {};

    for (int k0 = 0; k0 < K; k0 += 32) {
        load_lds16(Ah + gA0 + k0, ldsW + 0);
        load_lds16(Ah + gA1 + k0, ldsW + 4096);
        load_lds16(Al + gA0 + k0, ldsW + 8192);
        load_lds16(Al + gA1 + k0, ldsW + 12288);
        load_lds16(Bh + gB0 + k0, ldsW + 16384);
        load_lds16(Bh + gB1 + k0, ldsW + 20480);
        load_lds16(Bl + gB0 + k0, ldsW + 24576);
        load_lds16(Bl + gB1 + k0, ldsW + 28672);
        __syncthreads();

        short8 ah[4], al[4], bh[4], bl[4];
        #pragma unroll
        for (int m = 0; m < 4; ++m) {
            ah[m] = *(const short8*)(smem + 0    + offA + m * 1024);
            al[m] = *(const short8*)(smem + 8192 + offA + m * 1024);
        }
        #pragma unroll
        for (int n = 0; n < 4; ++n) {
            bh[n] = *(const short8*)(smem + 16384 + offB + n * 1024);
            bl[n] = *(const short8*)(smem + 24576 + offB + n * 1024);
        }
        #pragma unroll
        for (int m = 0; m < 4; ++m)
            #pragma unroll
            for (int n = 0; n < 4; ++n) {
                acc[m][n] = __builtin_amdgcn_mfma_f32_16x16x32_bf16(ah[m], bh[n], acc[m][n], 0, 0, 0);
                acc[m][n] = __builtin_amdgcn_mfma_f32_16x16x32_bf16(ah[m], bl[n], acc[m][n], 0, 0, 0);
                acc[m][n] = __builtin_amdgcn_mfma_f32_16x16x32_bf16(al[m], bh[n], acc[m][n], 0, 0, 0);
            }
        __syncthreads();
    }

    const int rowb = m0 + wr * 64 + (l >> 4) * 4;
    const int colb = n0 + wc * 64 + col16;
    float bv[4];
    #pragma unroll
    for (int n = 0; n < 4; ++n) bv[n] = bias[colb + n * 16];
    #pragma unroll
    for (int m = 0; m < 4; ++m)
        #pragma unroll
        for (int j = 0; j < 4; ++j) {
            float* crow = C + (size_t)(rowb + m * 16 + j) * N + colb;
            #pragma unroll
            for (int n = 0; n < 4; ++n) crow[n * 16] = acc[m][n][j] + bv[n];
        }
}

// qkv f32 [B*S][3072] -> Qbf (scaled 0.125) / Kbf: [BH][S][64] bf16; VbfT: [BH][64][S] bf16
__global__ __launch_bounds__(256) void repack(const float* __restrict__ qkv,
        unsigned short* __restrict__ Qbf, unsigned short* __restrict__ Kbf,
        unsigned short* __restrict__ VbfT) {
    __shared__ float Vt[64][65];
    const int t = threadIdx.x;
    const int s0 = blockIdx.x * 64;
    const int bh = blockIdx.y;
    const int h = bh & 15, b = bh >> 4;
    const size_t rs = 3072;
    #pragma unroll
    for (int p = 0; p < 4; ++p) {
        int sl = (t >> 4) + p * 16;
        int d4 = (t & 15) * 4;
        const float* base = qkv + ((size_t)(b * 2048 + s0 + sl)) * rs + h * 192 + d4;
        float4 q4 = *(const float4*)(base);
        float4 k4 = *(const float4*)(base + 64);
        float4 v4 = *(const float4*)(base + 128);
        ushort4 qo, ko;
        qo.x = f2bf(q4.x * 0.125f); qo.y = f2bf(q4.y * 0.125f);
        qo.z = f2bf(q4.z * 0.125f); qo.w = f2bf(q4.w * 0.125f);
        ko.x = f2bf(k4.x); ko.y = f2bf(k4.y); ko.z = f2bf(k4.z); ko.w = f2bf(k4.w);
        size_t o = ((size_t)bh * 2048 + s0 + sl) * 64 + d4;
        *(ushort4*)(Qbf + o) = qo;
        *(ushort4*)(Kbf + o) = ko;
        Vt[sl][d4 + 0] = v4.x; Vt[sl][d4 + 1] = v4.y;
        Vt[sl][d4 + 2] = v4.z; Vt[sl][d4 + 3] = v4.w;
    }
    __syncthreads();
    const int d = t >> 2;
    const int sl0 = (t & 3) * 16;
    ushort8 lo, hi;
    #pragma unroll
    for (int i = 0; i < 8; ++i) lo[i] = f2bf(Vt[sl0 + i][d]);
    #pragma unroll
    for (int i = 0; i < 8; ++i) hi[i] = f2bf(Vt[sl0 + 8 + i][d]);
    size_t o = ((size_t)bh * 64 + d) * 2048 + s0 + sl0;
    *(ushort8*)(VbfT + o) = lo;
    *(ushort8*)(VbfT + o + 8) = hi;
}

// MFMA flash attention. Grid (S/64, B*H), 256 threads = 4 waves; wave w owns q-rows
// [w*16, w*16+16). Swapped QK^T: S^T = mfma(K, Q) -> lane holds q-col = lane&15.
// LDS: Ks[64key][128B] @0, VsT[64d][128B] @8192, Ps[64q][128B] @16384; 16B slots
// XOR-swizzled by (row&7).
__global__ __launch_bounds__(256, 2) void mfma_attn(
    const unsigned short* __restrict__ Qbf, const unsigned short* __restrict__ Kbf,
    const unsigned short* __restrict__ VbfT, float* __restrict__ vals) {
    __shared__ __align__(1024) unsigned char smem[24576];
    const int tid = threadIdx.x;
    const int l = tid & 63, w = tid >> 6;
    const int g = l >> 4, c16 = l & 15;
    const int bh = blockIdx.y, q0 = blockIdx.x * 64;
    const int h = bh & 15, b = bh >> 4;

    // Q B-fragments (register-resident for all KV tiles)
    short8 qf[2];
    {
        const unsigned short* qp = Qbf + ((size_t)bh * 2048 + q0 + w * 16 + c16) * 64 + g * 8;
        qf[0] = *(const short8*)(qp);
        qf[1] = *(const short8*)(qp + 32);
    }
    f32x4 o[4] = {};            // PV accum: fc=0..3 (d-groups), rows q=(g*4+j)
    float mrun = -INFINITY, lsum = 0.f;

    const int srow = l >> 3, sslot = l & 7;     // staging: lane covers row srow, slot sslot
    const unsigned short* Kg = Kbf + (size_t)bh * 2048 * 64;
    const unsigned short* Vg = VbfT + (size_t)bh * 64 * 2048;

    for (int kt0 = 0; kt0 < 2048; kt0 += 64) {
        __syncthreads();   // prior tile's Ks/VsT reads complete
        {
            int r0 = w * 16 + srow, r1 = r0 + 8;
            load_lds16(Kg + (size_t)(kt0 + r0) * 64 + (sslot ^ (r0 & 7)) * 8, smem + w * 2048);
            load_lds16(Kg + (size_t)(kt0 + r1) * 64 + (sslot ^ (r1 & 7)) * 8, smem + w * 2048 + 1024);
            load_lds16(Vg + (size_t)r0 * 2048 + kt0 + (sslot ^ (r0 & 7)) * 8, smem + 8192 + w * 2048);
            load_lds16(Vg + (size_t)r1 * 2048 + kt0 + (sslot ^ (r1 & 7)) * 8, smem + 8192 + w * 2048 + 1024);
        }
        __syncthreads();   // staging complete (compiler drains vmcnt)

        // ---- S^T = K @ Q^T : s[kt][j] = S[key=kt*16+g*4+j][q=c16] ----
        f32x4 s[4];
        #pragma unroll
        for (int kt = 0; kt < 4; ++kt) {
            int row = kt * 16 + c16;
            short8 a0 = *(const short8*)(smem + row * 128 + ((g ^ (row & 7)) * 16));
            short8 a1 = *(const short8*)(smem + row * 128 + (((4 + g) ^ (row & 7)) * 16));
            f32x4 z = {};
            z = __builtin_amdgcn_mfma_f32_16x16x32_bf16(a0, qf[0], z, 0, 0, 0);
            z = __builtin_amdgcn_mfma_f32_16x16x32_bf16(a1, qf[1], z, 0, 0, 0);
            s[kt] = z;
        }

        // ---- online softmax for q-column c16 ----
        float pmax = s[0][0];
        #pragma unroll
        for (int kt = 0; kt < 4; ++kt)
            #pragma unroll
            for (int j = 0; j < 4; ++j) pmax = fmaxf(pmax, s[kt][j]);
        pmax = fmaxf(pmax, __shfl_xor(pmax, 16, 64));
        pmax = fmaxf(pmax, __shfl_xor(pmax, 32, 64));
        float mnew = fmaxf(mrun, pmax);
        float corr = __expf(mrun - mnew);
        mrun = mnew;
        float p[4][4];
        float rsum = 0.f;
        #pragma unroll
        for (int kt = 0; kt < 4; ++kt)
            #pragma unroll
            for (int j = 0; j < 4; ++j) {
                p[kt][j] = __expf(s[kt][j] - mnew);
                rsum += p[kt][j];
            }
        rsum += __shfl_xor(rsum, 16, 64);
        rsum += __shfl_xor(rsum, 32, 64);
        lsum = lsum * corr + rsum;

        // ---- P -> bf16 -> Ps (wave-private rows; same-wave write->read) ----
        {
            int row = w * 16 + c16;
            #pragma unroll
            for (int kt = 0; kt < 4; ++kt) {
                uint2 val;
                val.x = pack2bf(p[kt][0], p[kt][1]);
                val.y = pack2bf(p[kt][2], p[kt][3]);
                int slot = (kt * 2 + (g >> 1)) ^ (row & 7);
                *(uint2*)(smem + 16384 + row * 128 + slot * 16 + (g & 1) * 8) = val;
            }
        }
        asm volatile("" ::: "memory");

        // ---- rescale O by corr (broadcast to O-row layout) ----
        #pragma unroll
        for (int j = 0; j < 4; ++j) {
            float cj = __shfl(corr, g * 4 + j, 64);
            #pragma unroll
            for (int fc = 0; fc < 4; ++fc) o[fc][j] *= cj;
        }

        // ---- O += P @ V  (A = P from Ps, B = V^T from VsT) ----
        {
            int prow = w * 16 + c16;
            short8 pa0 = *(const short8*)(smem + 16384 + prow * 128 + ((g ^ (prow & 7)) * 16));
            short8 pa1 = *(const short8*)(smem + 16384 + prow * 128 + (((4 + g) ^ (prow & 7)) * 16));
            #pragma unroll
            for (int fc = 0; fc < 4; ++fc) {
                int vrow = fc * 16 + c16;
                short8 vb0 = *(const short8*)(smem + 8192 + vrow * 128 + ((g ^ (vrow & 7)) * 16));
                short8 vb1 = *(const short8*)(smem + 8192 + vrow * 128 + (((4 + g) ^ (vrow & 7)) * 16));
                o[fc] = __builtin_amdgcn_mfma_f32_16x16x32_bf16(pa0, vb0, o[fc], 0, 0, 0);
                o[fc] = __builtin_amdgcn_mfma_f32_16x16x32_bf16(pa1, vb1, o[fc], 0, 0, 0);
            }
        }
    }

    // ---- epilogue: vals[b, q0 + w*16 + g*4 + j, h*64 + fc*16 + c16] ----
    float inv = 1.f / lsum;
    float* ob = vals + ((size_t)(b * 2048 + q0 + w * 16)) * 1024 + h * 64;
    #pragma unroll
    for (int j = 0; j < 4; ++j) {
        float vj = __shfl(inv, g * 4 + j, 64);
        #pragma unroll
        for (int fc = 0; fc < 4; ++fc)
            ob[(size_t)(g * 4 + j) * 1024 + fc * 16 + c16] = o[fc][j] * vj;
    }
}

extern "C" void kernel_launch(void* const* d_in, const int* in_sizes, int n_in,
                              void* d_out, int out_size, void* d_ws, size_t ws_size,
                              hipStream_t stream) {
    const float* x     = (const float*)d_in[0];
    const float* w_qkv = (const float*)d_in[1];
    const float* b_qkv = (const float*)d_in[2];
    const float* w_o   = (const float*)d_in[3];
    const float* b_o   = (const float*)d_in[4];
    float* out = (float*)d_out;

    const int B = 2, S = 2048, D = 1024;
    const int M = B * S;          // 4096
    const int N1 = 3 * D;         // 3072
    const int BH = B * NHEADS;    // 32

    float* qkv  = (float*)d_ws;                       // [4096,3072] f32
    float* vals = qkv + (size_t)M * N1;               // [4096,1024] f32
    unsigned short* xh  = (unsigned short*)(vals + (size_t)M * D);
    unsigned short* xl  = xh  + (size_t)M * D;
    unsigned short* wqh = xl  + (size_t)M * D;
    unsigned short* wql = wqh + (size_t)N1 * D;
    unsigned short* woh = wql + (size_t)N1 * D;
    unsigned short* wol = woh + (size_t)D * D;
    unsigned short* Qbf = wol + (size_t)D * D;        // [BH,2048,64] bf16
    unsigned short* Kbf = Qbf + (size_t)BH * S * HD;
    unsigned short* VbfT= Kbf + (size_t)BH * S * HD;  // [BH,64,2048] bf16
    unsigned short* vh = xh;   // reuse after GEMM1
    unsigned short* vl = xl;

    split_kernel<<<(M * D) / 1024, 256, 0, stream>>>(x, xh, xl, M * D);
    split_kernel<<<(N1 * D) / 1024, 256, 0, stream>>>(w_qkv, wqh, wql, N1 * D);
    split_kernel<<<(D * D) / 1024, 256, 0, stream>>>(w_o, woh, wol, D * D);

    // 1) qkv = x @ w_qkv^T + b_qkv
    gemm_split<<<dim3(N1 / 128, M / 128), 256, 0, stream>>>(xh, xl, wqh, wql, b_qkv, qkv, M, N1, D);

    // 2) repack to bf16 attention layouts
    repack<<<dim3(S / 64, BH), 256, 0, stream>>>(qkv, Qbf, Kbf, VbfT);

    // 3) MFMA flash attention
    mfma_attn<<<dim3(S / 64, BH), 256, 0, stream>>>(Qbf, Kbf, VbfT, vals);

    // 4) out = vals @ w_o^T + b_o
    split_kernel<<<(M * D) / 1024, 256, 0, stream>>>(vals, vh, vl, M * D);
    gemm_split<<<dim3(D / 128, M / 128), 256, 0, stream>>>(vh, vl, woh, wol, b_o, out, M, D, D);
}

// Round 5
// 221.751 us; speedup vs baseline: 27.3799x; 1.0500x over previous
//
#include <hip/hip_runtime.h>
#include <math.h>

#define NHEADS 16
#define HD 64

typedef __attribute__((ext_vector_type(8))) short short8;
typedef __attribute__((ext_vector_type(4))) float f32x4;

__device__ inline unsigned short f2bf(float f) {
    unsigned int u = __float_as_uint(f);
    u += 0x7fff + ((u >> 16) & 1);
    return (unsigned short)(u >> 16);
}
__device__ inline float bf2f(unsigned short h) {
    return __uint_as_float(((unsigned int)h) << 16);
}
__device__ inline void load_lds16(const void* g, void* l) {
    __builtin_amdgcn_global_load_lds(
        (const __attribute__((address_space(1))) unsigned int*)g,
        (__attribute__((address_space(3))) unsigned int*)l, 16, 0, 0);
}

// fp32 -> (hi bf16, lo bf16), elementwise, 4/thread
__global__ void split_kernel(const float* __restrict__ in, unsigned short* __restrict__ hi,
                             unsigned short* __restrict__ lo, int n) {
    int i = (blockIdx.x * blockDim.x + threadIdx.x) * 4;
    if (i >= n) return;
    float4 v = *(const float4*)(in + i);
    ushort4 h, l;
    h.x = f2bf(v.x); l.x = f2bf(v.x - bf2f(h.x));
    h.y = f2bf(v.y); l.y = f2bf(v.y - bf2f(h.y));
    h.z = f2bf(v.z); l.z = f2bf(v.z - bf2f(h.z));
    h.w = f2bf(v.w); l.w = f2bf(v.w - bf2f(h.w));
    *(ushort4*)(hi + i) = h;
    *(ushort4*)(lo + i) = l;
}

// ---- shared GEMM core macro-ish: 128x128 tile, BK=32, split-bf16 (3 MFMA) ----
#define GEMM_CORE(K)                                                                   \
    __shared__ __align__(1024) unsigned char smem[32768];                              \
    const int tid = threadIdx.x;                                                       \
    const int l = tid & 63, w = tid >> 6;                                              \
    const int wr = w >> 1, wc = w & 1;                                                 \
    const int m0 = blockIdx.y * 128, n0 = blockIdx.x * 128;                            \
    const int srow = tid >> 2;                                                         \
    const int schunk = (tid & 3) ^ ((srow >> 1) & 3);                                  \
    const size_t gA0 = (size_t)(m0 + srow) * K + schunk * 8;                           \
    const size_t gA1 = gA0 + (size_t)64 * K;                                           \
    const size_t gB0 = (size_t)(n0 + srow) * K + schunk * 8;                           \
    const size_t gB1 = gB0 + (size_t)64 * K;                                           \
    unsigned char* ldsW = smem + w * 1024;                                             \
    const int col16 = l & 15, kc = l >> 4;                                             \
    const int ra0 = wr * 64 + col16;                                                   \
    const int offA = ra0 * 64 + ((kc ^ ((ra0 >> 1) & 3)) * 16);                        \
    const int rb0 = wc * 64 + col16;                                                   \
    const int offB = rb0 * 64 + ((kc ^ ((rb0 >> 1) & 3)) * 16);                        \
    f32x4 acc[4][4] = {};                                                              \
    for (int k0 = 0; k0 < K; k0 += 32) {                                               \
        load_lds16(Ah + gA0 + k0, ldsW + 0);                                           \
        load_lds16(Ah + gA1 + k0, ldsW + 4096);                                        \
        load_lds16(Al + gA0 + k0, ldsW + 8192);                                        \
        load_lds16(Al + gA1 + k0, ldsW + 12288);                                       \
        load_lds16(Bh + gB0 + k0, ldsW + 16384);                                       \
        load_lds16(Bh + gB1 + k0, ldsW + 20480);                                       \
        load_lds16(Bl + gB0 + k0, ldsW + 24576);                                       \
        load_lds16(Bl + gB1 + k0, ldsW + 28672);                                       \
        __syncthreads();                                                               \
        short8 ah[4], al[4], bh[4], bl[4];                                             \
        _Pragma("unroll")                                                              \
        for (int m = 0; m < 4; ++m) {                                                  \
            ah[m] = *(const short8*)(smem + 0    + offA + m * 1024);                   \
            al[m] = *(const short8*)(smem + 8192 + offA + m * 1024);                   \
        }                                                                              \
        _Pragma("unroll")                                                              \
        for (int n = 0; n < 4; ++n) {                                                  \
            bh[n] = *(const short8*)(smem + 16384 + offB + n * 1024);                  \
            bl[n] = *(const short8*)(smem + 24576 + offB + n * 1024);                  \
        }                                                                              \
        _Pragma("unroll")                                                              \
        for (int m = 0; m < 4; ++m)                                                    \
            _Pragma("unroll")                                                          \
            for (int n = 0; n < 4; ++n) {                                              \
                acc[m][n] = __builtin_amdgcn_mfma_f32_16x16x32_bf16(ah[m], bh[n], acc[m][n], 0, 0, 0); \
                acc[m][n] = __builtin_amdgcn_mfma_f32_16x16x32_bf16(ah[m], bl[n], acc[m][n], 0, 0, 0); \
                acc[m][n] = __builtin_amdgcn_mfma_f32_16x16x32_bf16(al[m], bh[n], acc[m][n], 0, 0, 0); \
            }                                                                          \
        __syncthreads();                                                               \
    }

// C[M,N] = (Ah+Al)(Bh+Bl)^T + bias, f32 out
__global__ __launch_bounds__(256, 2) void gemm_split(
    const unsigned short* __restrict__ Ah, const unsigned short* __restrict__ Al,
    const unsigned short* __restrict__ Bh, const unsigned short* __restrict__ Bl,
    const float* __restrict__ bias, float* __restrict__ C,
    int M, int N, int K) {
    GEMM_CORE(K)
    const int rowb = m0 + wr * 64 + (l >> 4) * 4;
    const int colb = n0 + wc * 64 + col16;
    float bv[4];
    #pragma unroll
    for (int n = 0; n < 4; ++n) bv[n] = bias[colb + n * 16];
    #pragma unroll
    for (int m = 0; m < 4; ++m)
        #pragma unroll
        for (int j = 0; j < 4; ++j) {
            float* crow = C + (size_t)(rowb + m * 16 + j) * N + colb;
            #pragma unroll
            for (int n = 0; n < 4; ++n) crow[n * 16] = acc[m][n][j] + bv[n];
        }
}

// QKV GEMM with fused epilogue: writes Qbf (scaled 0.125*log2e) / Kbf [bh][s][64] and
// VbfT [bh][d][s] directly in bf16. qkv col = h*192 + part*64 + d.
#define QSCALE 0.18033688f
__global__ __launch_bounds__(256, 2) void gemm_qkv(
    const unsigned short* __restrict__ Ah, const unsigned short* __restrict__ Al,
    const unsigned short* __restrict__ Bh, const unsigned short* __restrict__ Bl,
    const float* __restrict__ bias,
    unsigned short* __restrict__ Qbf, unsigned short* __restrict__ Kbf,
    unsigned short* __restrict__ VbfT, int K) {
    GEMM_CORE(K)
    const int rowb = m0 + wr * 64 + (l >> 4) * 4;
    const int colb = n0 + wc * 64 + col16;
    #pragma unroll
    for (int n = 0; n < 4; ++n) {
        int col = colb + n * 16;
        int h = col / 192;
        int rem = col - h * 192;
        int part = rem >> 6, d = rem & 63;   // wave-uniform part/h
        float bv = bias[col];
        #pragma unroll
        for (int m = 0; m < 4; ++m) {
            int r0 = rowb + m * 16;
            int b = r0 >> 11, s0r = r0 & 2047;
            int bh = b * 16 + h;
            if (part == 0) {
                #pragma unroll
                for (int j = 0; j < 4; ++j)
                    Qbf[((size_t)bh * 2048 + s0r + j) * 64 + d] =
                        f2bf((acc[m][n][j] + bv) * QSCALE);
            } else if (part == 1) {
                #pragma unroll
                for (int j = 0; j < 4; ++j)
                    Kbf[((size_t)bh * 2048 + s0r + j) * 64 + d] = f2bf(acc[m][n][j] + bv);
            } else {
                ushort4 pk;
                pk.x = f2bf(acc[m][n][0] + bv);
                pk.y = f2bf(acc[m][n][1] + bv);
                pk.z = f2bf(acc[m][n][2] + bv);
                pk.w = f2bf(acc[m][n][3] + bv);
                *(ushort4*)&VbfT[((size_t)bh * 64 + d) * 2048 + s0r] = pk;
            }
        }
    }
}

// MFMA flash attention, KVBLK=128, double-buffered K/V, 1 barrier/tile.
// LDS: K0 @0, K1 @16K, V0 @32K, V1 @48K (each [rows][128 or 256B], XOR-swizzled
// 16B slots), Ps @64K ([64 q][256B]). Softmax in base-2 (Q pre-scaled by log2e).
__global__ __launch_bounds__(256, 2) void mfma_attn(
    const unsigned short* __restrict__ Qbf, const unsigned short* __restrict__ Kbf,
    const unsigned short* __restrict__ VbfT,
    unsigned short* __restrict__ vh, unsigned short* __restrict__ vl) {
    __shared__ __align__(1024) unsigned char smem[81920];
    const int tid = threadIdx.x;
    const int l = tid & 63, w = tid >> 6;
    const int g = l >> 4, c16 = l & 15;
    const int bh = blockIdx.y, q0 = blockIdx.x * 64;
    const int h = bh & 15, b = bh >> 4;

    short8 qf[2];
    {
        const unsigned short* qp = Qbf + ((size_t)bh * 2048 + q0 + w * 16 + c16) * 64 + g * 8;
        qf[0] = *(const short8*)(qp);
        qf[1] = *(const short8*)(qp + 32);
    }
    f32x4 o[4] = {};
    float mrun = -INFINITY, lsum = 0.f;

    const unsigned short* Kg = Kbf + (size_t)bh * 2048 * 64;
    const unsigned short* Vg = VbfT + (size_t)bh * 64 * 2048;
    const int rK = w * 32 + (l >> 3), sK = l & 7;     // K staging: 128 rows x 8 slots
    const int dV = w * 16 + (l >> 4), sV = l & 15;    // V staging: 64 rows x 16 slots
    const int prow = w * 16 + c16;

    #define STAGE(kt0, buf)                                                            \
        {                                                                              \
            unsigned char* bK = smem + (buf) * 16384 + w * 4096;                       \
            unsigned char* bV = smem + 32768 + (buf) * 16384 + w * 4096;               \
            _Pragma("unroll")                                                          \
            for (int i = 0; i < 4; ++i) {                                              \
                int r = rK + i * 8;                                                    \
                load_lds16(Kg + (size_t)((kt0) + r) * 64 + ((sK ^ (r & 7)) * 8), bK + i * 1024); \
            }                                                                          \
            _Pragma("unroll")                                                          \
            for (int i = 0; i < 4; ++i) {                                              \
                int d = dV + i * 4;                                                    \
                load_lds16(Vg + (size_t)d * 2048 + (kt0) + ((sV ^ (d & 7)) * 8), bV + i * 1024); \
            }                                                                          \
        }

    STAGE(0, 0)
    __syncthreads();
    int cur = 0;
    const int NT = 2048 / 128;
    for (int t = 0; t < NT; ++t) {
        if (t + 1 < NT) STAGE((t + 1) * 128, cur ^ 1)
        const unsigned char* Ksb = smem + cur * 16384;
        const unsigned char* Vsb = smem + 32768 + cur * 16384;

        // ---- S^T = K @ Q^T, 128 keys ----
        f32x4 s[8];
        __builtin_amdgcn_s_setprio(1);
        #pragma unroll
        for (int kt = 0; kt < 8; ++kt) {
            int row = kt * 16 + c16;
            short8 a0 = *(const short8*)(Ksb + row * 128 + ((g ^ (row & 7)) * 16));
            short8 a1 = *(const short8*)(Ksb + row * 128 + (((4 + g) ^ (row & 7)) * 16));
            f32x4 z = {};
            z = __builtin_amdgcn_mfma_f32_16x16x32_bf16(a0, qf[0], z, 0, 0, 0);
            z = __builtin_amdgcn_mfma_f32_16x16x32_bf16(a1, qf[1], z, 0, 0, 0);
            s[kt] = z;
        }
        __builtin_amdgcn_s_setprio(0);

        // ---- online softmax (base-2), defer-max ----
        float pmax = s[0][0];
        #pragma unroll
        for (int kt = 0; kt < 8; ++kt)
            pmax = fmaxf(pmax, fmaxf(fmaxf(s[kt][0], s[kt][1]), fmaxf(s[kt][2], s[kt][3])));
        pmax = fmaxf(pmax, __shfl_xor(pmax, 16, 64));
        pmax = fmaxf(pmax, __shfl_xor(pmax, 32, 64));
        bool nodef = !__all(pmax <= mrun + 11.5f);
        float corr = 1.f;
        if (nodef) {
            float mnew = fmaxf(mrun, pmax);
            corr = exp2f(mrun - mnew);
            mrun = mnew;
        }
        float rsum = 0.f;
        unsigned int pw[16];
        #pragma unroll
        for (int kt = 0; kt < 8; ++kt) {
            float p0 = exp2f(s[kt][0] - mrun), p1 = exp2f(s[kt][1] - mrun);
            float p2 = exp2f(s[kt][2] - mrun), p3 = exp2f(s[kt][3] - mrun);
            rsum += (p0 + p1) + (p2 + p3);
            asm("v_cvt_pk_bf16_f32 %0, %1, %2" : "=v"(pw[kt * 2 + 0]) : "v"(p0), "v"(p1));
            asm("v_cvt_pk_bf16_f32 %0, %1, %2" : "=v"(pw[kt * 2 + 1]) : "v"(p2), "v"(p3));
        }
        rsum += __shfl_xor(rsum, 16, 64);
        rsum += __shfl_xor(rsum, 32, 64);
        lsum = lsum * corr + rsum;

        // ---- write P to Ps (wave-private rows) ----
        {
            unsigned char* Pb = smem + 65536 + prow * 256 + (g & 1) * 8;
            #pragma unroll
            for (int kt = 0; kt < 8; ++kt) {
                int slot = (kt * 2 + (g >> 1)) ^ (prow & 7);
                uint2 v; v.x = pw[kt * 2]; v.y = pw[kt * 2 + 1];
                *(uint2*)(Pb + slot * 16) = v;
            }
        }
        if (nodef) {
            #pragma unroll
            for (int j = 0; j < 4; ++j) {
                float cj = __shfl(corr, g * 4 + j, 64);
                #pragma unroll
                for (int fc = 0; fc < 4; ++fc) o[fc][j] *= cj;
            }
        }
        asm volatile("" ::: "memory");

        // ---- O += P @ V ----
        short8 pa[4];
        #pragma unroll
        for (int c = 0; c < 4; ++c)
            pa[c] = *(const short8*)(smem + 65536 + prow * 256 + (((c * 4 + g) ^ (prow & 7)) * 16));
        __builtin_amdgcn_s_setprio(1);
        #pragma unroll
        for (int fc = 0; fc < 4; ++fc) {
            int vrow = fc * 16 + c16;
            #pragma unroll
            for (int c = 0; c < 4; ++c) {
                short8 vb = *(const short8*)(Vsb + vrow * 256 + (((c * 4 + g) ^ (vrow & 7)) * 16));
                o[fc] = __builtin_amdgcn_mfma_f32_16x16x32_bf16(pa[c], vb, o[fc], 0, 0, 0);
            }
        }
        __builtin_amdgcn_s_setprio(0);
        __syncthreads();
        cur ^= 1;
    }

    // ---- epilogue: split-bf16 write of O/lsum ----
    float inv = 1.f / lsum;
    size_t ob = ((size_t)(b * 2048 + q0 + w * 16)) * 1024 + h * 64;
    #pragma unroll
    for (int j = 0; j < 4; ++j) {
        float vj = __shfl(inv, g * 4 + j, 64);
        #pragma unroll
        for (int fc = 0; fc < 4; ++fc) {
            float val = o[fc][j] * vj;
            unsigned short hi_ = f2bf(val);
            size_t idx = ob + (size_t)(g * 4 + j) * 1024 + fc * 16 + c16;
            vh[idx] = hi_;
            vl[idx] = f2bf(val - bf2f(hi_));
        }
    }
}

extern "C" void kernel_launch(void* const* d_in, const int* in_sizes, int n_in,
                              void* d_out, int out_size, void* d_ws, size_t ws_size,
                              hipStream_t stream) {
    const float* x     = (const float*)d_in[0];
    const float* w_qkv = (const float*)d_in[1];
    const float* b_qkv = (const float*)d_in[2];
    const float* w_o   = (const float*)d_in[3];
    const float* b_o   = (const float*)d_in[4];
    float* out = (float*)d_out;

    const int B = 2, S = 2048, D = 1024;
    const int M = B * S;          // 4096
    const int N1 = 3 * D;         // 3072
    const int BH = B * NHEADS;    // 32

    unsigned short* xh  = (unsigned short*)d_ws;      // [4096,1024]
    unsigned short* xl  = xh  + (size_t)M * D;
    unsigned short* wqh = xl  + (size_t)M * D;        // [3072,1024]
    unsigned short* wql = wqh + (size_t)N1 * D;
    unsigned short* woh = wql + (size_t)N1 * D;       // [1024,1024]
    unsigned short* wol = woh + (size_t)D * D;
    unsigned short* Qbf = wol + (size_t)D * D;        // [32,2048,64]
    unsigned short* Kbf = Qbf + (size_t)BH * S * HD;
    unsigned short* VbfT= Kbf + (size_t)BH * S * HD;  // [32,64,2048]
    unsigned short* vh = xh;   // reuse after gemm_qkv
    unsigned short* vl = xl;

    split_kernel<<<(M * D) / 1024, 256, 0, stream>>>(x, xh, xl, M * D);
    split_kernel<<<(N1 * D) / 1024, 256, 0, stream>>>(w_qkv, wqh, wql, N1 * D);
    split_kernel<<<(D * D) / 1024, 256, 0, stream>>>(w_o, woh, wol, D * D);

    // 1) fused QKV projection -> bf16 attention layouts
    gemm_qkv<<<dim3(N1 / 128, M / 128), 256, 0, stream>>>(xh, xl, wqh, wql, b_qkv,
                                                          Qbf, Kbf, VbfT, D);

    // 2) MFMA flash attention -> split-bf16 vals
    mfma_attn<<<dim3(S / 64, BH), 256, 0, stream>>>(Qbf, Kbf, VbfT, vh, vl);

    // 3) out = vals @ w_o^T + b_o
    gemm_split<<<dim3(D / 128, M / 128), 256, 0, stream>>>(vh, vl, woh, wol, b_o, out, M, D, D);
}

// Round 6
// 209.050 us; speedup vs baseline: 29.0434x; 1.0608x over previous
//
#include <hip/hip_runtime.h>
#include <math.h>

#define NHEADS 16
#define HD 64

typedef __attribute__((ext_vector_type(8))) short short8;
typedef __attribute__((ext_vector_type(4))) float f32x4;
typedef __attribute__((ext_vector_type(16))) float f32x16;
typedef __attribute__((ext_vector_type(4))) unsigned int u32x4;

__device__ inline unsigned short f2bf(float f) {
    unsigned int u = __float_as_uint(f);
    u += 0x7fff + ((u >> 16) & 1);
    return (unsigned short)(u >> 16);
}
__device__ inline float bf2f(unsigned short h) {
    return __uint_as_float(((unsigned int)h) << 16);
}
__device__ inline void load_lds16(const void* g, void* l) {
    __builtin_amdgcn_global_load_lds(
        (const __attribute__((address_space(1))) unsigned int*)g,
        (__attribute__((address_space(3))) unsigned int*)l, 16, 0, 0);
}
// v_permlane32_swap: x' = [lo: x.lo | hi: y.lo-of-other-half], y' = [lo: x.hi | hi: y.hi]
__device__ inline void pl32swap(unsigned int& x, unsigned int& y) {
    asm volatile("v_permlane32_swap_b32 %0, %1" : "+v"(x), "+v"(y));
}

// fp32 -> (hi bf16, lo bf16), elementwise, 4/thread
__global__ void split_kernel(const float* __restrict__ in, unsigned short* __restrict__ hi,
                             unsigned short* __restrict__ lo, int n) {
    int i = (blockIdx.x * blockDim.x + threadIdx.x) * 4;
    if (i >= n) return;
    float4 v = *(const float4*)(in + i);
    ushort4 h, l;
    h.x = f2bf(v.x); l.x = f2bf(v.x - bf2f(h.x));
    h.y = f2bf(v.y); l.y = f2bf(v.y - bf2f(h.y));
    h.z = f2bf(v.z); l.z = f2bf(v.z - bf2f(h.z));
    h.w = f2bf(v.w); l.w = f2bf(v.w - bf2f(h.w));
    *(ushort4*)(hi + i) = h;
    *(ushort4*)(lo + i) = l;
}

// ---- shared GEMM core: 128x128 tile, BK=32, split-bf16 (3 MFMA) ----
#define GEMM_CORE(K)                                                                   \
    __shared__ __align__(1024) unsigned char smem[32768];                              \
    const int tid = threadIdx.x;                                                       \
    const int l = tid & 63, w = tid >> 6;                                              \
    const int wr = w >> 1, wc = w & 1;                                                 \
    const int m0 = blockIdx.y * 128, n0 = blockIdx.x * 128;                            \
    const int srow = tid >> 2;                                                         \
    const int schunk = (tid & 3) ^ ((srow >> 1) & 3);                                  \
    const size_t gA0 = (size_t)(m0 + srow) * K + schunk * 8;                           \
    const size_t gA1 = gA0 + (size_t)64 * K;                                           \
    const size_t gB0 = (size_t)(n0 + srow) * K + schunk * 8;                           \
    const size_t gB1 = gB0 + (size_t)64 * K;                                           \
    unsigned char* ldsW = smem + w * 1024;                                             \
    const int col16 = l & 15, kc = l >> 4;                                             \
    const int ra0 = wr * 64 + col16;                                                   \
    const int offA = ra0 * 64 + ((kc ^ ((ra0 >> 1) & 3)) * 16);                        \
    const int rb0 = wc * 64 + col16;                                                   \
    const int offB = rb0 * 64 + ((kc ^ ((rb0 >> 1) & 3)) * 16);                        \
    f32x4 acc[4][4] = {};                                                              \
    for (int k0 = 0; k0 < K; k0 += 32) {                                               \
        load_lds16(Ah + gA0 + k0, ldsW + 0);                                           \
        load_lds16(Ah + gA1 + k0, ldsW + 4096);                                        \
        load_lds16(Al + gA0 + k0, ldsW + 8192);                                        \
        load_lds16(Al + gA1 + k0, ldsW + 12288);                                       \
        load_lds16(Bh + gB0 + k0, ldsW + 16384);                                       \
        load_lds16(Bh + gB1 + k0, ldsW + 20480);                                       \
        load_lds16(Bl + gB0 + k0, ldsW + 24576);                                       \
        load_lds16(Bl + gB1 + k0, ldsW + 28672);                                       \
        __syncthreads();                                                               \
        short8 ah[4], al[4], bh[4], bl[4];                                             \
        _Pragma("unroll")                                                              \
        for (int m = 0; m < 4; ++m) {                                                  \
            ah[m] = *(const short8*)(smem + 0    + offA + m * 1024);                   \
            al[m] = *(const short8*)(smem + 8192 + offA + m * 1024);                   \
        }                                                                              \
        _Pragma("unroll")                                                              \
        for (int n = 0; n < 4; ++n) {                                                  \
            bh[n] = *(const short8*)(smem + 16384 + offB + n * 1024);                  \
            bl[n] = *(const short8*)(smem + 24576 + offB + n * 1024);                  \
        }                                                                              \
        _Pragma("unroll")                                                              \
        for (int m = 0; m < 4; ++m)                                                    \
            _Pragma("unroll")                                                          \
            for (int n = 0; n < 4; ++n) {                                              \
                acc[m][n] = __builtin_amdgcn_mfma_f32_16x16x32_bf16(ah[m], bh[n], acc[m][n], 0, 0, 0); \
                acc[m][n] = __builtin_amdgcn_mfma_f32_16x16x32_bf16(ah[m], bl[n], acc[m][n], 0, 0, 0); \
                acc[m][n] = __builtin_amdgcn_mfma_f32_16x16x32_bf16(al[m], bh[n], acc[m][n], 0, 0, 0); \
            }                                                                          \
        __syncthreads();                                                               \
    }

// C[M,N] = (Ah+Al)(Bh+Bl)^T + bias, f32 out
__global__ __launch_bounds__(256, 2) void gemm_split(
    const unsigned short* __restrict__ Ah, const unsigned short* __restrict__ Al,
    const unsigned short* __restrict__ Bh, const unsigned short* __restrict__ Bl,
    const float* __restrict__ bias, float* __restrict__ C,
    int M, int N, int K) {
    GEMM_CORE(K)
    const int rowb = m0 + wr * 64 + (l >> 4) * 4;
    const int colb = n0 + wc * 64 + col16;
    float bv[4];
    #pragma unroll
    for (int n = 0; n < 4; ++n) bv[n] = bias[colb + n * 16];
    #pragma unroll
    for (int m = 0; m < 4; ++m)
        #pragma unroll
        for (int j = 0; j < 4; ++j) {
            float* crow = C + (size_t)(rowb + m * 16 + j) * N + colb;
            #pragma unroll
            for (int n = 0; n < 4; ++n) crow[n * 16] = acc[m][n][j] + bv[n];
        }
}

// QKV GEMM, fused epilogue -> Qbf (scaled 0.125*log2e) / Kbf [bh][s][64], VbfT [bh][d][s]
#define QSCALE 0.18033688f
__global__ __launch_bounds__(256, 2) void gemm_qkv(
    const unsigned short* __restrict__ Ah, const unsigned short* __restrict__ Al,
    const unsigned short* __restrict__ Bh, const unsigned short* __restrict__ Bl,
    const float* __restrict__ bias,
    unsigned short* __restrict__ Qbf, unsigned short* __restrict__ Kbf,
    unsigned short* __restrict__ VbfT, int K) {
    GEMM_CORE(K)
    const int rowb = m0 + wr * 64 + (l >> 4) * 4;
    const int colb = n0 + wc * 64 + col16;
    #pragma unroll
    for (int n = 0; n < 4; ++n) {
        int col = colb + n * 16;
        int h = col / 192;
        int rem = col - h * 192;
        int part = rem >> 6, d = rem & 63;
        float bv = bias[col];
        #pragma unroll
        for (int m = 0; m < 4; ++m) {
            int r0 = rowb + m * 16;
            int b = r0 >> 11, s0r = r0 & 2047;
            int bh = b * 16 + h;
            if (part == 0) {
                #pragma unroll
                for (int j = 0; j < 4; ++j)
                    Qbf[((size_t)bh * 2048 + s0r + j) * 64 + d] =
                        f2bf((acc[m][n][j] + bv) * QSCALE);
            } else if (part == 1) {
                #pragma unroll
                for (int j = 0; j < 4; ++j)
                    Kbf[((size_t)bh * 2048 + s0r + j) * 64 + d] = f2bf(acc[m][n][j] + bv);
            } else {
                ushort4 pk;
                pk.x = f2bf(acc[m][n][0] + bv);
                pk.y = f2bf(acc[m][n][1] + bv);
                pk.z = f2bf(acc[m][n][2] + bv);
                pk.w = f2bf(acc[m][n][3] + bv);
                *(ushort4*)&VbfT[((size_t)bh * 64 + d) * 2048 + s0r] = pk;
            }
        }
    }
}

// MFMA flash attention, 32x32 shape, in-register P.
// Grid (S/128, B*H), 4 waves; wave w owns q [w*32, w*32+32). KVBLK=64, double-buffered.
// S^T = mfma32(K, Q): lane q = l&31, keys per lane = 32/tile (half per lane-pair).
// LDS: K0 @0, K1 @8K, V0 @16K, V1 @24K; rows 128B, 16B slots XOR-swizzled by (row&7).
__global__ __launch_bounds__(256, 2) void mfma_attn(
    const unsigned short* __restrict__ Qbf, const unsigned short* __restrict__ Kbf,
    const unsigned short* __restrict__ VbfT,
    unsigned short* __restrict__ vh, unsigned short* __restrict__ vl) {
    __shared__ __align__(1024) unsigned char smem[32768];
    const int tid = threadIdx.x;
    const int l = tid & 63, w = tid >> 6;
    const int l31 = l & 31, hl = l >> 5;
    const int bh = blockIdx.y, q0 = blockIdx.x * 128;
    const int h = bh & 15, b = bh >> 4;

    // Q B-fragments: qf[kc] holds Q[q=l31][d = kc*16 + hl*8 + i]
    short8 qf[4];
    {
        const unsigned short* qp = Qbf + ((size_t)bh * 2048 + q0 + w * 32 + l31) * 64 + hl * 8;
        #pragma unroll
        for (int c = 0; c < 4; ++c) qf[c] = *(const short8*)(qp + c * 16);
    }
    f32x16 o0 = {}, o1 = {};   // O^T[d][q]: dc=0/1, d=(r&3)+8*(r>>2)+4*hl+32*dc, q=l31
    float mrun = -INFINITY, lsum = 0.f;

    const unsigned short* Kg = Kbf + (size_t)bh * 2048 * 64;
    const unsigned short* Vg = VbfT + (size_t)bh * 64 * 2048;

    #define STAGE(kt0, buf)                                                            \
        {                                                                              \
            unsigned char* bK = smem + (buf) * 8192 + w * 1024;                        \
            unsigned char* bV = smem + 16384 + (buf) * 8192 + w * 1024;                \
            _Pragma("unroll")                                                          \
            for (int i = 0; i < 2; ++i) {                                              \
                int r = i * 32 + w * 8 + (l >> 3);                                     \
                int s_ = l & 7;                                                        \
                load_lds16(Kg + (size_t)((kt0) + r) * 64 + ((s_ ^ (r & 7)) * 8), bK + i * 4096); \
                load_lds16(Vg + (size_t)r * 2048 + (kt0) + ((s_ ^ (r & 7)) * 8), bV + i * 4096); \
            }                                                                          \
        }

    STAGE(0, 0)
    __syncthreads();
    int cur = 0;
    for (int t = 0; t < 32; ++t) {
        if (t + 1 < 32) STAGE((t + 1) * 64, cur ^ 1)
        const unsigned char* Ksb = smem + cur * 8192;
        const unsigned char* Vsb = smem + 16384 + cur * 8192;

        // ---- S^T = K @ Q^T (two 32-key chunks) ----
        f32x16 s0 = {}, s1 = {};
        __builtin_amdgcn_s_setprio(1);
        #pragma unroll
        for (int kc = 0; kc < 4; ++kc) {
            int row0 = l31, row1 = 32 + l31;
            short8 k0 = *(const short8*)(Ksb + row0 * 128 + (((kc * 2 + hl) ^ (row0 & 7)) * 16));
            short8 k1 = *(const short8*)(Ksb + row1 * 128 + (((kc * 2 + hl) ^ (row1 & 7)) * 16));
            s0 = __builtin_amdgcn_mfma_f32_32x32x16_bf16(k0, qf[kc], s0, 0, 0, 0);
            s1 = __builtin_amdgcn_mfma_f32_32x32x16_bf16(k1, qf[kc], s1, 0, 0, 0);
        }
        __builtin_amdgcn_s_setprio(0);

        // ---- online softmax (base-2), q lane-local; partner lane (xor 32) has other keys ----
        float pmax = s0[0];
        #pragma unroll
        for (int r = 0; r < 16; ++r) pmax = fmaxf(pmax, s0[r]);
        #pragma unroll
        for (int r = 0; r < 16; ++r) pmax = fmaxf(pmax, s1[r]);
        pmax = fmaxf(pmax, __shfl_xor(pmax, 32, 64));
        bool nodef = !__all(pmax <= mrun + 11.5f);
        float corr = 1.f;
        if (nodef) {
            float mnew = fmaxf(mrun, pmax);
            corr = exp2f(mrun - mnew);
            mrun = mnew;
        }
        float rsum = 0.f;
        unsigned int a[2][8];
        #pragma unroll
        for (int j = 0; j < 8; ++j) {
            float p0 = exp2f(s0[2 * j] - mrun), p1 = exp2f(s0[2 * j + 1] - mrun);
            rsum += p0 + p1;
            asm("v_cvt_pk_bf16_f32 %0, %1, %2" : "=v"(a[0][j]) : "v"(p0), "v"(p1));
        }
        #pragma unroll
        for (int j = 0; j < 8; ++j) {
            float p0 = exp2f(s1[2 * j] - mrun), p1 = exp2f(s1[2 * j + 1] - mrun);
            rsum += p0 + p1;
            asm("v_cvt_pk_bf16_f32 %0, %1, %2" : "=v"(a[1][j]) : "v"(p0), "v"(p1));
        }
        rsum += __shfl_xor(rsum, 32, 64);
        lsum = lsum * corr + rsum;
        if (nodef) {
            #pragma unroll
            for (int r = 0; r < 16; ++r) { o0[r] *= corr; o1[r] *= corr; }
        }

        // ---- P^T B-fragments in-register: 8 permlane32_swap, each yields 2 regs ----
        #pragma unroll
        for (int c = 0; c < 2; ++c) {
            pl32swap(a[c][0], a[c][2]);
            pl32swap(a[c][1], a[c][3]);
            pl32swap(a[c][4], a[c][6]);
            pl32swap(a[c][5], a[c][7]);
        }

        // ---- O^T += V^T @ P^T ----
        __builtin_amdgcn_s_setprio(1);
        #pragma unroll
        for (int kk = 0; kk < 4; ++kk) {   // 16-key chunks of the tile
            u32x4 pw;
            pw.x = a[kk >> 1][(kk & 1) * 4 + 0];
            pw.y = a[kk >> 1][(kk & 1) * 4 + 1];
            pw.z = a[kk >> 1][(kk & 1) * 4 + 2];
            pw.w = a[kk >> 1][(kk & 1) * 4 + 3];
            short8 pf = __builtin_bit_cast(short8, pw);
            int vrow0 = l31, vrow1 = 32 + l31;
            short8 v0 = *(const short8*)(Vsb + vrow0 * 128 + (((kk * 2 + hl) ^ (vrow0 & 7)) * 16));
            short8 v1 = *(const short8*)(Vsb + vrow1 * 128 + (((kk * 2 + hl) ^ (vrow1 & 7)) * 16));
            o0 = __builtin_amdgcn_mfma_f32_32x32x16_bf16(v0, pf, o0, 0, 0, 0);
            o1 = __builtin_amdgcn_mfma_f32_32x32x16_bf16(v1, pf, o1, 0, 0, 0);
        }
        __builtin_amdgcn_s_setprio(0);
        __syncthreads();
        cur ^= 1;
    }

    // ---- epilogue: vals[b, q0+w*32+q, h*64 + d] split-bf16, 8B stores ----
    float inv = 1.f / lsum;
    size_t orow = ((size_t)(b * 2048 + q0 + w * 32 + l31)) * 1024 + h * 64;
    #pragma unroll
    for (int dc = 0; dc < 2; ++dc) {
        const f32x16* op = dc ? &o1 : &o0;
        #pragma unroll
        for (int rq = 0; rq < 4; ++rq) {
            int d0 = dc * 32 + rq * 8 + hl * 4;
            ushort4 hv, lv;
            #pragma unroll
            for (int j = 0; j < 4; ++j) {
                float val = (*op)[rq * 4 + j] * inv;
                unsigned short hi_ = f2bf(val);
                ((unsigned short*)&hv)[j] = hi_;
                ((unsigned short*)&lv)[j] = f2bf(val - bf2f(hi_));
            }
            *(ushort4*)(vh + orow + d0) = hv;
            *(ushort4*)(vl + orow + d0) = lv;
        }
    }
}

extern "C" void kernel_launch(void* const* d_in, const int* in_sizes, int n_in,
                              void* d_out, int out_size, void* d_ws, size_t ws_size,
                              hipStream_t stream) {
    const float* x     = (const float*)d_in[0];
    const float* w_qkv = (const float*)d_in[1];
    const float* b_qkv = (const float*)d_in[2];
    const float* w_o   = (const float*)d_in[3];
    const float* b_o   = (const float*)d_in[4];
    float* out = (float*)d_out;

    const int B = 2, S = 2048, D = 1024;
    const int M = B * S;          // 4096
    const int N1 = 3 * D;         // 3072
    const int BH = B * NHEADS;    // 32

    unsigned short* xh  = (unsigned short*)d_ws;      // [4096,1024]
    unsigned short* xl  = xh  + (size_t)M * D;
    unsigned short* wqh = xl  + (size_t)M * D;        // [3072,1024]
    unsigned short* wql = wqh + (size_t)N1 * D;
    unsigned short* woh = wql + (size_t)N1 * D;       // [1024,1024]
    unsigned short* wol = woh + (size_t)D * D;
    unsigned short* Qbf = wol + (size_t)D * D;        // [32,2048,64]
    unsigned short* Kbf = Qbf + (size_t)BH * S * HD;
    unsigned short* VbfT= Kbf + (size_t)BH * S * HD;  // [32,64,2048]
    unsigned short* vh = xh;   // reuse after gemm_qkv
    unsigned short* vl = xl;

    split_kernel<<<(M * D) / 1024, 256, 0, stream>>>(x, xh, xl, M * D);
    split_kernel<<<(N1 * D) / 1024, 256, 0, stream>>>(w_qkv, wqh, wql, N1 * D);
    split_kernel<<<(D * D) / 1024, 256, 0, stream>>>(w_o, woh, wol, D * D);

    // 1) fused QKV projection -> bf16 attention layouts
    gemm_qkv<<<dim3(N1 / 128, M / 128), 256, 0, stream>>>(xh, xl, wqh, wql, b_qkv,
                                                          Qbf, Kbf, VbfT, D);

    // 2) MFMA flash attention (32x32, in-register P) -> split-bf16 vals
    mfma_attn<<<dim3(S / 128, BH), 256, 0, stream>>>(Qbf, Kbf, VbfT, vh, vl);

    // 3) out = vals @ w_o^T + b_o
    gemm_split<<<dim3(D / 128, M / 128), 256, 0, stream>>>(vh, vl, woh, wol, b_o, out, M, D, D);
}

// Round 7
// 142.307 us; speedup vs baseline: 42.6648x; 1.4690x over previous
//
#include <hip/hip_runtime.h>
#include <math.h>

#define NHEADS 16
#define HD 64

typedef __attribute__((ext_vector_type(8))) _Float16 half8;
typedef __attribute__((ext_vector_type(4))) _Float16 half4;
typedef __attribute__((ext_vector_type(4))) float f32x4;
typedef __attribute__((ext_vector_type(16))) float f32x16;
typedef __attribute__((ext_vector_type(4))) unsigned int u32x4;

__device__ inline void load_lds16(const void* g, void* l) {
    __builtin_amdgcn_global_load_lds(
        (const __attribute__((address_space(1))) unsigned int*)g,
        (__attribute__((address_space(3))) unsigned int*)l, 16, 0, 0);
}
__device__ inline void pl32swap(unsigned int& x, unsigned int& y) {
    asm volatile("v_permlane32_swap_b32 %0, %1" : "+v"(x), "+v"(y));
}

// fp32 -> fp16, 8/thread
__global__ void cvt_f16(const float* __restrict__ in, _Float16* __restrict__ out, int n) {
    int i = (blockIdx.x * blockDim.x + threadIdx.x) * 8;
    if (i >= n) return;
    float4 a = *(const float4*)(in + i);
    float4 b = *(const float4*)(in + i + 4);
    half8 h;
    h[0] = (_Float16)a.x; h[1] = (_Float16)a.y; h[2] = (_Float16)a.z; h[3] = (_Float16)a.w;
    h[4] = (_Float16)b.x; h[5] = (_Float16)b.y; h[6] = (_Float16)b.z; h[7] = (_Float16)b.w;
    *(half8*)(out + i) = h;
}

// ---- shared GEMM core: 128x128 tile, BK=32, f16 MFMA ----
// LDS: A[128][32] @0 (8KB), B[128][32] @8192; rows 64B, 16B slots XOR-swizzled.
#define GEMM_CORE(K)                                                                   \
    __shared__ __align__(1024) unsigned char smem[16384];                              \
    const int tid = threadIdx.x;                                                       \
    const int l = tid & 63, w = tid >> 6;                                              \
    const int wr = w >> 1, wc = w & 1;                                                 \
    const int m0 = blockIdx.y * 128, n0 = blockIdx.x * 128;                            \
    const int srow = tid >> 2;                                                         \
    const int schunk = (tid & 3) ^ ((srow >> 1) & 3);                                  \
    const size_t gA0 = (size_t)(m0 + srow) * K + schunk * 8;                           \
    const size_t gA1 = gA0 + (size_t)64 * K;                                           \
    const size_t gB0 = (size_t)(n0 + srow) * K + schunk * 8;                           \
    const size_t gB1 = gB0 + (size_t)64 * K;                                           \
    unsigned char* ldsW = smem + w * 1024;                                             \
    const int col16 = l & 15, kc = l >> 4;                                             \
    const int ra0 = wr * 64 + col16;                                                   \
    const int offA = ra0 * 64 + ((kc ^ ((ra0 >> 1) & 3)) * 16);                        \
    const int rb0 = wc * 64 + col16;                                                   \
    const int offB = rb0 * 64 + ((kc ^ ((rb0 >> 1) & 3)) * 16);                        \
    f32x4 acc[4][4] = {};                                                              \
    for (int k0 = 0; k0 < K; k0 += 32) {                                               \
        load_lds16(A + gA0 + k0, ldsW + 0);                                            \
        load_lds16(A + gA1 + k0, ldsW + 4096);                                         \
        load_lds16(B + gB0 + k0, ldsW + 8192);                                         \
        load_lds16(B + gB1 + k0, ldsW + 12288);                                       \
        __syncthreads();                                                               \
        half8 af[4], bf[4];                                                            \
        _Pragma("unroll")                                                              \
        for (int m = 0; m < 4; ++m) af[m] = *(const half8*)(smem + offA + m * 1024);   \
        _Pragma("unroll")                                                              \
        for (int n = 0; n < 4; ++n) bf[n] = *(const half8*)(smem + 8192 + offB + n * 1024); \
        _Pragma("unroll")                                                              \
        for (int m = 0; m < 4; ++m)                                                    \
            _Pragma("unroll")                                                          \
            for (int n = 0; n < 4; ++n)                                                \
                acc[m][n] = __builtin_amdgcn_mfma_f32_16x16x32_f16(af[m], bf[n], acc[m][n], 0, 0, 0); \
        __syncthreads();                                                               \
    }

// out[M,N] = A[M,K] @ B[N,K]^T + bias, f32 out
__global__ __launch_bounds__(256, 2) void gemm_o(
    const _Float16* __restrict__ A, const _Float16* __restrict__ B,
    const float* __restrict__ bias, float* __restrict__ C,
    int M, int N, int K) {
    GEMM_CORE(K)
    const int rowb = m0 + wr * 64 + (l >> 4) * 4;
    const int colb = n0 + wc * 64 + col16;
    float bv[4];
    #pragma unroll
    for (int n = 0; n < 4; ++n) bv[n] = bias[colb + n * 16];
    #pragma unroll
    for (int m = 0; m < 4; ++m)
        #pragma unroll
        for (int j = 0; j < 4; ++j) {
            float* crow = C + (size_t)(rowb + m * 16 + j) * N + colb;
            #pragma unroll
            for (int n = 0; n < 4; ++n) crow[n * 16] = acc[m][n][j] + bv[n];
        }
}

// QKV GEMM, fused epilogue -> Qf (scaled 0.125*log2e) / Kf [bh][s][64], VfT [bh][d][s]
#define QSCALE 0.18033688f
__global__ __launch_bounds__(256, 2) void gemm_qkv(
    const _Float16* __restrict__ A, const _Float16* __restrict__ B,
    const float* __restrict__ bias,
    _Float16* __restrict__ Qf, _Float16* __restrict__ Kf,
    _Float16* __restrict__ VfT, int K) {
    GEMM_CORE(K)
    const int rowb = m0 + wr * 64 + (l >> 4) * 4;
    const int colb = n0 + wc * 64 + col16;
    #pragma unroll
    for (int n = 0; n < 4; ++n) {
        int col = colb + n * 16;
        int h = col / 192;
        int rem = col - h * 192;
        int part = rem >> 6, d = rem & 63;   // wave-uniform
        float bv = bias[col];
        #pragma unroll
        for (int m = 0; m < 4; ++m) {
            int r0 = rowb + m * 16;
            int b = r0 >> 11, s0r = r0 & 2047;
            int bh = b * 16 + h;
            if (part == 0) {
                #pragma unroll
                for (int j = 0; j < 4; ++j)
                    Qf[((size_t)bh * 2048 + s0r + j) * 64 + d] =
                        (_Float16)((acc[m][n][j] + bv) * QSCALE);
            } else if (part == 1) {
                #pragma unroll
                for (int j = 0; j < 4; ++j)
                    Kf[((size_t)bh * 2048 + s0r + j) * 64 + d] = (_Float16)(acc[m][n][j] + bv);
            } else {
                half4 pk;
                pk[0] = (_Float16)(acc[m][n][0] + bv);
                pk[1] = (_Float16)(acc[m][n][1] + bv);
                pk[2] = (_Float16)(acc[m][n][2] + bv);
                pk[3] = (_Float16)(acc[m][n][3] + bv);
                *(half4*)&VfT[((size_t)bh * 64 + d) * 2048 + s0r] = pk;
            }
        }
    }
}

// MFMA flash attention, 32x32 f16, in-register P.
// Grid (S/128, B*H), 4 waves; wave w owns q [w*32, w*32+32). KVBLK=64, double-buffered.
// LDS: K0 @0, K1 @8K, V0 @16K, V1 @24K; rows 128B, 16B slots XOR-swizzled by (row&7).
__global__ __launch_bounds__(256, 2) void mfma_attn(
    const _Float16* __restrict__ Qf, const _Float16* __restrict__ Kf,
    const _Float16* __restrict__ VfT, _Float16* __restrict__ vals) {
    __shared__ __align__(1024) unsigned char smem[32768];
    const int tid = threadIdx.x;
    const int l = tid & 63, w = tid >> 6;
    const int l31 = l & 31, hl = l >> 5;
    const int bh = blockIdx.y, q0 = blockIdx.x * 128;
    const int h = bh & 15, b = bh >> 4;

    half8 qf[4];
    {
        const _Float16* qp = Qf + ((size_t)bh * 2048 + q0 + w * 32 + l31) * 64 + hl * 8;
        #pragma unroll
        for (int c = 0; c < 4; ++c) qf[c] = *(const half8*)(qp + c * 16);
    }
    f32x16 o0 = {}, o1 = {};   // O^T[d][q]
    float mrun = -INFINITY, lsum = 0.f;

    const _Float16* Kg = Kf + (size_t)bh * 2048 * 64;
    const _Float16* Vg = VfT + (size_t)bh * 64 * 2048;

    #define STAGE(kt0, buf)                                                            \
        {                                                                              \
            unsigned char* bK = smem + (buf) * 8192 + w * 1024;                        \
            unsigned char* bV = smem + 16384 + (buf) * 8192 + w * 1024;                \
            _Pragma("unroll")                                                          \
            for (int i = 0; i < 2; ++i) {                                              \
                int r = i * 32 + w * 8 + (l >> 3);                                     \
                int s_ = l & 7;                                                        \
                load_lds16(Kg + (size_t)((kt0) + r) * 64 + ((s_ ^ (r & 7)) * 8), bK + i * 4096); \
                load_lds16(Vg + (size_t)r * 2048 + (kt0) + ((s_ ^ (r & 7)) * 8), bV + i * 4096); \
            }                                                                          \
        }

    STAGE(0, 0)
    __syncthreads();
    int cur = 0;
    for (int t = 0; t < 32; ++t) {
        if (t + 1 < 32) STAGE((t + 1) * 64, cur ^ 1)
        const unsigned char* Ksb = smem + cur * 8192;
        const unsigned char* Vsb = smem + 16384 + cur * 8192;

        // ---- S^T = K @ Q^T ----
        f32x16 s0 = {}, s1 = {};
        __builtin_amdgcn_s_setprio(1);
        #pragma unroll
        for (int kc = 0; kc < 4; ++kc) {
            int row0 = l31, row1 = 32 + l31;
            half8 k0 = *(const half8*)(Ksb + row0 * 128 + (((kc * 2 + hl) ^ (row0 & 7)) * 16));
            half8 k1 = *(const half8*)(Ksb + row1 * 128 + (((kc * 2 + hl) ^ (row1 & 7)) * 16));
            s0 = __builtin_amdgcn_mfma_f32_32x32x16_f16(k0, qf[kc], s0, 0, 0, 0);
            s1 = __builtin_amdgcn_mfma_f32_32x32x16_f16(k1, qf[kc], s1, 0, 0, 0);
        }
        __builtin_amdgcn_s_setprio(0);

        // ---- online softmax (base-2), q lane-local ----
        float pmax = s0[0];
        #pragma unroll
        for (int r = 0; r < 16; ++r) pmax = fmaxf(pmax, s0[r]);
        #pragma unroll
        for (int r = 0; r < 16; ++r) pmax = fmaxf(pmax, s1[r]);
        pmax = fmaxf(pmax, __shfl_xor(pmax, 32, 64));
        bool nodef = !__all(pmax <= mrun + 11.5f);
        float corr = 1.f;
        if (nodef) {
            float mnew = fmaxf(mrun, pmax);
            corr = exp2f(mrun - mnew);
            mrun = mnew;
        }
        float rsum = 0.f;
        unsigned int a[2][8];
        #pragma unroll
        for (int j = 0; j < 8; ++j) {
            float p0 = exp2f(s0[2 * j] - mrun), p1 = exp2f(s0[2 * j + 1] - mrun);
            rsum += p0 + p1;
            asm("v_cvt_pkrtz_f16_f32 %0, %1, %2" : "=v"(a[0][j]) : "v"(p0), "v"(p1));
        }
        #pragma unroll
        for (int j = 0; j < 8; ++j) {
            float p0 = exp2f(s1[2 * j] - mrun), p1 = exp2f(s1[2 * j + 1] - mrun);
            rsum += p0 + p1;
            asm("v_cvt_pkrtz_f16_f32 %0, %1, %2" : "=v"(a[1][j]) : "v"(p0), "v"(p1));
        }
        rsum += __shfl_xor(rsum, 32, 64);
        lsum = lsum * corr + rsum;
        if (nodef) {
            #pragma unroll
            for (int r = 0; r < 16; ++r) { o0[r] *= corr; o1[r] *= corr; }
        }

        // ---- P^T B-fragments in-register ----
        #pragma unroll
        for (int c = 0; c < 2; ++c) {
            pl32swap(a[c][0], a[c][2]);
            pl32swap(a[c][1], a[c][3]);
            pl32swap(a[c][4], a[c][6]);
            pl32swap(a[c][5], a[c][7]);
        }

        // ---- O^T += V^T @ P^T ----
        __builtin_amdgcn_s_setprio(1);
        #pragma unroll
        for (int kk = 0; kk < 4; ++kk) {
            u32x4 pw;
            pw.x = a[kk >> 1][(kk & 1) * 4 + 0];
            pw.y = a[kk >> 1][(kk & 1) * 4 + 1];
            pw.z = a[kk >> 1][(kk & 1) * 4 + 2];
            pw.w = a[kk >> 1][(kk & 1) * 4 + 3];
            half8 pf = __builtin_bit_cast(half8, pw);
            int vrow0 = l31, vrow1 = 32 + l31;
            half8 v0 = *(const half8*)(Vsb + vrow0 * 128 + (((kk * 2 + hl) ^ (vrow0 & 7)) * 16));
            half8 v1 = *(const half8*)(Vsb + vrow1 * 128 + (((kk * 2 + hl) ^ (vrow1 & 7)) * 16));
            o0 = __builtin_amdgcn_mfma_f32_32x32x16_f16(v0, pf, o0, 0, 0, 0);
            o1 = __builtin_amdgcn_mfma_f32_32x32x16_f16(v1, pf, o1, 0, 0, 0);
        }
        __builtin_amdgcn_s_setprio(0);
        __syncthreads();
        cur ^= 1;
    }

    // ---- epilogue: vals[b, q0+w*32+q, h*64+d] f16 ----
    float inv = 1.f / lsum;
    size_t orow = ((size_t)(b * 2048 + q0 + w * 32 + l31)) * 1024 + h * 64;
    #pragma unroll
    for (int dc = 0; dc < 2; ++dc) {
        const f32x16* op = dc ? &o1 : &o0;
        #pragma unroll
        for (int rq = 0; rq < 4; ++rq) {
            int d0 = dc * 32 + rq * 8 + hl * 4;
            half4 hv;
            #pragma unroll
            for (int j = 0; j < 4; ++j) hv[j] = (_Float16)((*op)[rq * 4 + j] * inv);
            *(half4*)(vals + orow + d0) = hv;
        }
    }
}

extern "C" void kernel_launch(void* const* d_in, const int* in_sizes, int n_in,
                              void* d_out, int out_size, void* d_ws, size_t ws_size,
                              hipStream_t stream) {
    const float* x     = (const float*)d_in[0];
    const float* w_qkv = (const float*)d_in[1];
    const float* b_qkv = (const float*)d_in[2];
    const float* w_o   = (const float*)d_in[3];
    const float* b_o   = (const float*)d_in[4];
    float* out = (float*)d_out;

    const int B = 2, S = 2048, D = 1024;
    const int M = B * S;          // 4096
    const int N1 = 3 * D;         // 3072
    const int BH = B * NHEADS;    // 32

    _Float16* xf  = (_Float16*)d_ws;                  // [4096,1024]
    _Float16* wqf = xf  + (size_t)M * D;              // [3072,1024]
    _Float16* wof = wqf + (size_t)N1 * D;             // [1024,1024]
    _Float16* Qf  = wof + (size_t)D * D;              // [32,2048,64]
    _Float16* Kf  = Qf  + (size_t)BH * S * HD;
    _Float16* VfT = Kf  + (size_t)BH * S * HD;        // [32,64,2048]
    _Float16* vals = xf;   // reuse x-f16 space after gemm_qkv

    cvt_f16<<<(M * D) / 2048, 256, 0, stream>>>(x, xf, M * D);
    cvt_f16<<<(N1 * D) / 2048, 256, 0, stream>>>(w_qkv, wqf, N1 * D);
    cvt_f16<<<(D * D) / 2048, 256, 0, stream>>>(w_o, wof, D * D);

    // 1) fused QKV projection -> f16 attention layouts
    gemm_qkv<<<dim3(N1 / 128, M / 128), 256, 0, stream>>>(xf, wqf, b_qkv, Qf, Kf, VfT, D);

    // 2) MFMA flash attention (32x32 f16, in-register P)
    mfma_attn<<<dim3(S / 128, BH), 256, 0, stream>>>(Qf, Kf, VfT, vals);

    // 3) out = vals @ w_o^T + b_o
    gemm_o<<<dim3(D / 128, M / 128), 256, 0, stream>>>(vals, wof, b_o, out, M, D, D);
}

// Round 8
// 129.870 us; speedup vs baseline: 46.7507x; 1.0958x over previous
//
#include <hip/hip_runtime.h>
#include <math.h>

#define NHEADS 16
#define HD 64

typedef __attribute__((ext_vector_type(8))) _Float16 half8;
typedef __attribute__((ext_vector_type(4))) _Float16 half4;
typedef __attribute__((ext_vector_type(4))) float f32x4;
typedef __attribute__((ext_vector_type(16))) float f32x16;
typedef __attribute__((ext_vector_type(4))) unsigned int u32x4;

__device__ inline void load_lds16(const void* g, void* l) {
    __builtin_amdgcn_global_load_lds(
        (const __attribute__((address_space(1))) unsigned int*)g,
        (__attribute__((address_space(3))) unsigned int*)l, 16, 0, 0);
}
__device__ inline void pl32swap(unsigned int& x, unsigned int& y) {
    asm volatile("v_permlane32_swap_b32 %0, %1" : "+v"(x), "+v"(y));
}

// fp32 -> fp16, 8/thread
__global__ void cvt_f16(const float* __restrict__ in, _Float16* __restrict__ out, int n) {
    int i = (blockIdx.x * blockDim.x + threadIdx.x) * 8;
    if (i >= n) return;
    float4 a = *(const float4*)(in + i);
    float4 b = *(const float4*)(in + i + 4);
    half8 h;
    h[0] = (_Float16)a.x; h[1] = (_Float16)a.y; h[2] = (_Float16)a.z; h[3] = (_Float16)a.w;
    h[4] = (_Float16)b.x; h[5] = (_Float16)b.y; h[6] = (_Float16)b.z; h[7] = (_Float16)b.w;
    *(half8*)(out + i) = h;
}

// ---- shared GEMM core: 128x128 tile, BK=32, f16 MFMA ----
#define GEMM_CORE(K)                                                                   \
    __shared__ __align__(1024) unsigned char smem[16384];                              \
    const int tid = threadIdx.x;                                                       \
    const int l = tid & 63, w = tid >> 6;                                              \
    const int wr = w >> 1, wc = w & 1;                                                 \
    const int m0 = blockIdx.y * 128, n0 = blockIdx.x * 128;                            \
    const int srow = tid >> 2;                                                         \
    const int schunk = (tid & 3) ^ ((srow >> 1) & 3);                                  \
    const size_t gA0 = (size_t)(m0 + srow) * K + schunk * 8;                           \
    const size_t gA1 = gA0 + (size_t)64 * K;                                           \
    const size_t gB0 = (size_t)(n0 + srow) * K + schunk * 8;                           \
    const size_t gB1 = gB0 + (size_t)64 * K;                                           \
    unsigned char* ldsW = smem + w * 1024;                                             \
    const int col16 = l & 15, kc = l >> 4;                                             \
    const int ra0 = wr * 64 + col16;                                                   \
    const int offA = ra0 * 64 + ((kc ^ ((ra0 >> 1) & 3)) * 16);                        \
    const int rb0 = wc * 64 + col16;                                                   \
    const int offB = rb0 * 64 + ((kc ^ ((rb0 >> 1) & 3)) * 16);                        \
    f32x4 acc[4][4] = {};                                                              \
    for (int k0 = 0; k0 < K; k0 += 32) {                                               \
        load_lds16(A + gA0 + k0, ldsW + 0);                                            \
        load_lds16(A + gA1 + k0, ldsW + 4096);                                         \
        load_lds16(B + gB0 + k0, ldsW + 8192);                                         \
        load_lds16(B + gB1 + k0, ldsW + 12288);                                       \
        __syncthreads();                                                               \
        half8 af[4], bf[4];                                                            \
        _Pragma("unroll")                                                              \
        for (int m = 0; m < 4; ++m) af[m] = *(const half8*)(smem + offA + m * 1024);   \
        _Pragma("unroll")                                                              \
        for (int n = 0; n < 4; ++n) bf[n] = *(const half8*)(smem + 8192 + offB + n * 1024); \
        _Pragma("unroll")                                                              \
        for (int m = 0; m < 4; ++m)                                                    \
            _Pragma("unroll")                                                          \
            for (int n = 0; n < 4; ++n)                                                \
                acc[m][n] = __builtin_amdgcn_mfma_f32_16x16x32_f16(af[m], bf[n], acc[m][n], 0, 0, 0); \
        __syncthreads();                                                               \
    }

// out[M,N] = A[M,K] @ B[N,K]^T + bias, f32 out
__global__ __launch_bounds__(256, 2) void gemm_o(
    const _Float16* __restrict__ A, const _Float16* __restrict__ B,
    const float* __restrict__ bias, float* __restrict__ C,
    int M, int N, int K) {
    GEMM_CORE(K)
    const int rowb = m0 + wr * 64 + (l >> 4) * 4;
    const int colb = n0 + wc * 64 + col16;
    float bv[4];
    #pragma unroll
    for (int n = 0; n < 4; ++n) bv[n] = bias[colb + n * 16];
    #pragma unroll
    for (int m = 0; m < 4; ++m)
        #pragma unroll
        for (int j = 0; j < 4; ++j) {
            float* crow = C + (size_t)(rowb + m * 16 + j) * N + colb;
            #pragma unroll
            for (int n = 0; n < 4; ++n) crow[n * 16] = acc[m][n][j] + bv[n];
        }
}

// QKV GEMM, fused epilogue -> Qf (scaled 0.125*log2e) / Kf [bh][s][64], VfT [bh][d][s]
#define QSCALE 0.18033688f
__global__ __launch_bounds__(256, 2) void gemm_qkv(
    const _Float16* __restrict__ A, const _Float16* __restrict__ B,
    const float* __restrict__ bias,
    _Float16* __restrict__ Qf, _Float16* __restrict__ Kf,
    _Float16* __restrict__ VfT, int K) {
    GEMM_CORE(K)
    const int rowb = m0 + wr * 64 + (l >> 4) * 4;
    const int colb = n0 + wc * 64 + col16;
    #pragma unroll
    for (int n = 0; n < 4; ++n) {
        int col = colb + n * 16;
        int h = col / 192;
        int rem = col - h * 192;
        int part = rem >> 6, d = rem & 63;   // wave-uniform
        float bv = bias[col];
        #pragma unroll
        for (int m = 0; m < 4; ++m) {
            int r0 = rowb + m * 16;
            int b = r0 >> 11, s0r = r0 & 2047;
            int bh = b * 16 + h;
            if (part == 0) {
                #pragma unroll
                for (int j = 0; j < 4; ++j)
                    Qf[((size_t)bh * 2048 + s0r + j) * 64 + d] =
                        (_Float16)((acc[m][n][j] + bv) * QSCALE);
            } else if (part == 1) {
                #pragma unroll
                for (int j = 0; j < 4; ++j)
                    Kf[((size_t)bh * 2048 + s0r + j) * 64 + d] = (_Float16)(acc[m][n][j] + bv);
            } else {
                half4 pk;
                pk[0] = (_Float16)(acc[m][n][0] + bv);
                pk[1] = (_Float16)(acc[m][n][1] + bv);
                pk[2] = (_Float16)(acc[m][n][2] + bv);
                pk[3] = (_Float16)(acc[m][n][3] + bv);
                *(half4*)&VfT[((size_t)bh * 64 + d) * 2048 + s0r] = pk;
            }
        }
    }
}

// MFMA flash attention, 32x32 f16, in-register P.
// Grid (S/128, B*H), 4 waves; wave w owns q [w*32, w*32+32). KVBLK=64, double-buffered.
// LDS geometry per K/V tile: 32 row-pairs x 16 slots of 16B ([row2][slot]); content of
// (row2, slot') is row (row2*2 + (slot>>3)), chunk (slot&7) with slot = slot' ^ (row2&15).
// -> all fragment reads are 2-way bank aliased (free). Buffers: K0 @0, K1 @8K, V0 @16K, V1 @24K.
__global__ __launch_bounds__(256, 2) void mfma_attn(
    const _Float16* __restrict__ Qf, const _Float16* __restrict__ Kf,
    const _Float16* __restrict__ VfT, _Float16* __restrict__ vals) {
    __shared__ __align__(1024) unsigned char smem[32768];
    const int tid = threadIdx.x;
    const int l = tid & 63, w = tid >> 6;
    const int l31 = l & 31, hl = l >> 5;
    const int bh = blockIdx.y, q0 = blockIdx.x * 128;
    const int h = bh & 15, b = bh >> 4;

    half8 qf[4];
    {
        const _Float16* qp = Qf + ((size_t)bh * 2048 + q0 + w * 32 + l31) * 64 + hl * 8;
        #pragma unroll
        for (int c = 0; c < 4; ++c) qf[c] = *(const half8*)(qp + c * 16);
    }
    f32x16 o0 = {}, o1 = {};   // O^T[d][q]
    float mrun = 0.f, lsum = 0.f;

    const _Float16* Kg = Kf + (size_t)bh * 2048 * 64;
    const _Float16* Vg = VfT + (size_t)bh * 64 * 2048;

    // ---- per-lane staging source offsets (elements), i = 0,1 ----
    int offK[2], offV[2];
    #pragma unroll
    for (int i = 0; i < 2; ++i) {
        int row2 = w * 8 + i * 4 + (l >> 4);
        int slot = (l & 15) ^ (row2 & 15);
        int row = row2 * 2 + (slot >> 3);   // key (K) or d (V)
        int chunk = slot & 7;
        offK[i] = row * 64 + chunk * 8;
        offV[i] = row * 2048 + chunk * 8;
    }
    // ---- per-lane fragment-read constants ----
    const int sbase = (l31 & 1) * 8;
    const int xr = (l31 >> 1) & 15;
    const int rb0 = (l31 >> 1) * 256;   // +4096 for rows 32..63

    #define STAGE(kt0, buf)                                                            \
        {                                                                              \
            unsigned char* bK = smem + (buf) * 8192 + w * 2048;                        \
            unsigned char* bV = smem + 16384 + (buf) * 8192 + w * 2048;                \
            load_lds16(Kg + (size_t)(kt0) * 64 + offK[0], bK);                         \
            load_lds16(Kg + (size_t)(kt0) * 64 + offK[1], bK + 1024);                  \
            load_lds16(Vg + (kt0) + offV[0], bV);                                      \
            load_lds16(Vg + (kt0) + offV[1], bV + 1024);                               \
        }

    STAGE(0, 0)
    __syncthreads();
    int cur = 0;
    for (int t = 0; t < 32; ++t) {
        if (t + 1 < 32) STAGE((t + 1) * 64, cur ^ 1)
        const unsigned char* Ksb = smem + cur * 8192;
        const unsigned char* Vsb = smem + 16384 + cur * 8192;

        // ---- S^T = K @ Q^T - mrun (subtract folded into MFMA C-init) ----
        f32x16 s0_, s1_;
        #pragma unroll
        for (int r = 0; r < 16; ++r) { s0_[r] = -mrun; s1_[r] = -mrun; }
        __builtin_amdgcn_s_setprio(1);
        #pragma unroll
        for (int kc = 0; kc < 4; ++kc) {
            int chOff = ((sbase + kc * 2 + hl) ^ xr) << 4;
            half8 k0 = *(const half8*)(Ksb + rb0 + chOff);
            half8 k1 = *(const half8*)(Ksb + rb0 + 4096 + chOff);
            s0_ = __builtin_amdgcn_mfma_f32_32x32x16_f16(k0, qf[kc], s0_, 0, 0, 0);
            s1_ = __builtin_amdgcn_mfma_f32_32x32x16_f16(k1, qf[kc], s1_, 0, 0, 0);
        }
        __builtin_amdgcn_s_setprio(0);

        // ---- pmax tree (shifted scores) ----
        float pm[8];
        #pragma unroll
        for (int j = 0; j < 8; ++j)
            pm[j] = fmaxf(fmaxf(s0_[2 * j], s0_[2 * j + 1]),
                          fmaxf(s1_[2 * j], s1_[2 * j + 1]));
        float pmax = fmaxf(fmaxf(fmaxf(pm[0], pm[1]), fmaxf(pm[2], pm[3])),
                           fmaxf(fmaxf(pm[4], pm[5]), fmaxf(pm[6], pm[7])));
        pmax = fmaxf(pmax, __shfl_xor(pmax, 32, 64));

        // ---- rare rescale path (defer-max; scores are shifted so bound is absolute) ----
        if (!__all(pmax <= 11.5f)) {
            float d = fmaxf(pmax, 0.f);
            #pragma unroll
            for (int r = 0; r < 16; ++r) { s0_[r] -= d; s1_[r] -= d; }
            float corr = __builtin_amdgcn_exp2f(-d);
            mrun += d;
            lsum *= corr;
            #pragma unroll
            for (int r = 0; r < 16; ++r) { o0[r] *= corr; o1[r] *= corr; }
        }

        // ---- exp2 + pack to f16 + row-sum ----
        float rsum = 0.f;
        unsigned int a[2][8];
        #pragma unroll
        for (int j = 0; j < 8; ++j) {
            float p0 = __builtin_amdgcn_exp2f(s0_[2 * j]);
            float p1 = __builtin_amdgcn_exp2f(s0_[2 * j + 1]);
            float q0 = __builtin_amdgcn_exp2f(s1_[2 * j]);
            float q1 = __builtin_amdgcn_exp2f(s1_[2 * j + 1]);
            rsum += (p0 + p1) + (q0 + q1);
            a[0][j] = __builtin_bit_cast(unsigned int, __builtin_amdgcn_cvt_pkrtz(p0, p1));
            a[1][j] = __builtin_bit_cast(unsigned int, __builtin_amdgcn_cvt_pkrtz(q0, q1));
        }
        rsum += __shfl_xor(rsum, 32, 64);
        lsum += rsum;

        // ---- P^T B-fragments in-register ----
        #pragma unroll
        for (int c = 0; c < 2; ++c) {
            pl32swap(a[c][0], a[c][2]);
            pl32swap(a[c][1], a[c][3]);
            pl32swap(a[c][4], a[c][6]);
            pl32swap(a[c][5], a[c][7]);
        }

        // ---- O^T += V^T @ P^T ----
        __builtin_amdgcn_s_setprio(1);
        #pragma unroll
        for (int kk = 0; kk < 4; ++kk) {
            u32x4 pw;
            pw.x = a[kk >> 1][(kk & 1) * 4 + 0];
            pw.y = a[kk >> 1][(kk & 1) * 4 + 1];
            pw.z = a[kk >> 1][(kk & 1) * 4 + 2];
            pw.w = a[kk >> 1][(kk & 1) * 4 + 3];
            half8 pf = __builtin_bit_cast(half8, pw);
            int chOff = ((sbase + kk * 2 + hl) ^ xr) << 4;
            half8 v0 = *(const half8*)(Vsb + rb0 + chOff);
            half8 v1 = *(const half8*)(Vsb + rb0 + 4096 + chOff);
            o0 = __builtin_amdgcn_mfma_f32_32x32x16_f16(v0, pf, o0, 0, 0, 0);
            o1 = __builtin_amdgcn_mfma_f32_32x32x16_f16(v1, pf, o1, 0, 0, 0);
        }
        __builtin_amdgcn_s_setprio(0);
        __syncthreads();
        cur ^= 1;
    }

    // ---- epilogue: vals[b, q0+w*32+q, h*64+d] f16 ----
    float inv = 1.f / lsum;
    size_t orow = ((size_t)(b * 2048 + q0 + w * 32 + l31)) * 1024 + h * 64;
    #pragma unroll
    for (int dc = 0; dc < 2; ++dc) {
        const f32x16* op = dc ? &o1 : &o0;
        #pragma unroll
        for (int rq = 0; rq < 4; ++rq) {
            int d0 = dc * 32 + rq * 8 + hl * 4;
            half4 hv;
            #pragma unroll
            for (int j = 0; j < 4; ++j) hv[j] = (_Float16)((*op)[rq * 4 + j] * inv);
            *(half4*)(vals + orow + d0) = hv;
        }
    }
}

extern "C" void kernel_launch(void* const* d_in, const int* in_sizes, int n_in,
                              void* d_out, int out_size, void* d_ws, size_t ws_size,
                              hipStream_t stream) {
    const float* x     = (const float*)d_in[0];
    const float* w_qkv = (const float*)d_in[1];
    const float* b_qkv = (const float*)d_in[2];
    const float* w_o   = (const float*)d_in[3];
    const float* b_o   = (const float*)d_in[4];
    float* out = (float*)d_out;

    const int B = 2, S = 2048, D = 1024;
    const int M = B * S;          // 4096
    const int N1 = 3 * D;         // 3072
    const int BH = B * NHEADS;    // 32

    _Float16* xf  = (_Float16*)d_ws;                  // [4096,1024]
    _Float16* wqf = xf  + (size_t)M * D;              // [3072,1024]
    _Float16* wof = wqf + (size_t)N1 * D;             // [1024,1024]
    _Float16* Qf  = wof + (size_t)D * D;              // [32,2048,64]
    _Float16* Kf  = Qf  + (size_t)BH * S * HD;
    _Float16* VfT = Kf  + (size_t)BH * S * HD;        // [32,64,2048]
    _Float16* vals = xf;   // reuse x-f16 space after gemm_qkv

    cvt_f16<<<(M * D) / 2048, 256, 0, stream>>>(x, xf, M * D);
    cvt_f16<<<(N1 * D) / 2048, 256, 0, stream>>>(w_qkv, wqf, N1 * D);
    cvt_f16<<<(D * D) / 2048, 256, 0, stream>>>(w_o, wof, D * D);

    // 1) fused QKV projection -> f16 attention layouts
    gemm_qkv<<<dim3(N1 / 128, M / 128), 256, 0, stream>>>(xf, wqf, b_qkv, Qf, Kf, VfT, D);

    // 2) MFMA flash attention (32x32 f16, in-register P)
    mfma_attn<<<dim3(S / 128, BH), 256, 0, stream>>>(Qf, Kf, VfT, vals);

    // 3) out = vals @ w_o^T + b_o
    gemm_o<<<dim3(D / 128, M / 128), 256, 0, stream>>>(vals, wof, b_o, out, M, D, D);
}

// Round 9
// 117.812 us; speedup vs baseline: 51.5357x; 1.1024x over previous
//
#include <hip/hip_runtime.h>
#include <math.h>

#define NHEADS 16
#define HD 64

typedef __attribute__((ext_vector_type(8))) _Float16 half8;
typedef __attribute__((ext_vector_type(4))) _Float16 half4;
typedef __attribute__((ext_vector_type(4))) float f32x4;
typedef __attribute__((ext_vector_type(16))) float f32x16;
typedef __attribute__((ext_vector_type(4))) unsigned int u32x4;

__device__ inline void load_lds16(const void* g, void* l) {
    __builtin_amdgcn_global_load_lds(
        (const __attribute__((address_space(1))) unsigned int*)g,
        (__attribute__((address_space(3))) unsigned int*)l, 16, 0, 0);
}
__device__ inline void pl32swap(unsigned int& x, unsigned int& y) {
    asm volatile("v_permlane32_swap_b32 %0, %1" : "+v"(x), "+v"(y));
}

// fp32 -> fp16 for x, w_qkv, w_o in ONE launch. Segment by flat index.
#define NX  4194304   // 4096*1024
#define NWQ 3145728   // 3072*1024
#define NWO 1048576   // 1024*1024
__global__ void cvt_all(const float* __restrict__ x, const float* __restrict__ wq,
                        const float* __restrict__ wo, _Float16* __restrict__ xf,
                        _Float16* __restrict__ wqf, _Float16* __restrict__ wof) {
    int i = (blockIdx.x * blockDim.x + threadIdx.x) * 8;
    const float* src; _Float16* dst; int off;
    if (i < NX)            { src = x;  dst = xf;  off = i; }
    else if (i < NX + NWQ) { src = wq; dst = wqf; off = i - NX; }
    else                   { src = wo; dst = wof; off = i - (NX + NWQ); }
    float4 a = *(const float4*)(src + off);
    float4 b = *(const float4*)(src + off + 4);
    half8 h;
    h[0] = (_Float16)a.x; h[1] = (_Float16)a.y; h[2] = (_Float16)a.z; h[3] = (_Float16)a.w;
    h[4] = (_Float16)b.x; h[5] = (_Float16)b.y; h[6] = (_Float16)b.z; h[7] = (_Float16)b.w;
    *(half8*)(dst + off) = h;
}

// ---- shared GEMM core: 128x128 tile, BK=32, f16 MFMA, XCD-swizzled blockIdx ----
#define GEMM_CORE(K)                                                                   \
    __shared__ __align__(1024) unsigned char smem[16384];                              \
    const int tid = threadIdx.x;                                                       \
    const int l = tid & 63, w = tid >> 6;                                              \
    const int wr = w >> 1, wc = w & 1;                                                 \
    const int nwg = gridDim.x * gridDim.y;                                             \
    const int bid = blockIdx.y * gridDim.x + blockIdx.x;                               \
    const int swz = (bid & 7) * (nwg >> 3) + (bid >> 3);                               \
    const int m0 = (swz / gridDim.x) * 128, n0 = (swz % gridDim.x) * 128;              \
    const int srow = tid >> 2;                                                         \
    const int schunk = (tid & 3) ^ ((srow >> 1) & 3);                                  \
    const size_t gA0 = (size_t)(m0 + srow) * K + schunk * 8;                           \
    const size_t gA1 = gA0 + (size_t)64 * K;                                           \
    const size_t gB0 = (size_t)(n0 + srow) * K + schunk * 8;                           \
    const size_t gB1 = gB0 + (size_t)64 * K;                                           \
    unsigned char* ldsW = smem + w * 1024;                                             \
    const int col16 = l & 15, kc = l >> 4;                                             \
    const int ra0 = wr * 64 + col16;                                                   \
    const int offA = ra0 * 64 + ((kc ^ ((ra0 >> 1) & 3)) * 16);                        \
    const int rb0 = wc * 64 + col16;                                                   \
    const int offB = rb0 * 64 + ((kc ^ ((rb0 >> 1) & 3)) * 16);                        \
    f32x4 acc[4][4] = {};                                                              \
    for (int k0 = 0; k0 < K; k0 += 32) {                                               \
        load_lds16(A + gA0 + k0, ldsW + 0);                                            \
        load_lds16(A + gA1 + k0, ldsW + 4096);                                         \
        load_lds16(B + gB0 + k0, ldsW + 8192);                                         \
        load_lds16(B + gB1 + k0, ldsW + 12288);                                       \
        __syncthreads();                                                               \
        half8 af[4], bf[4];                                                            \
        _Pragma("unroll")                                                              \
        for (int m = 0; m < 4; ++m) af[m] = *(const half8*)(smem + offA + m * 1024);   \
        _Pragma("unroll")                                                              \
        for (int n = 0; n < 4; ++n) bf[n] = *(const half8*)(smem + 8192 + offB + n * 1024); \
        _Pragma("unroll")                                                              \
        for (int m = 0; m < 4; ++m)                                                    \
            _Pragma("unroll")                                                          \
            for (int n = 0; n < 4; ++n)                                                \
                acc[m][n] = __builtin_amdgcn_mfma_f32_16x16x32_f16(af[m], bf[n], acc[m][n], 0, 0, 0); \
        __syncthreads();                                                               \
    }

// out[M,N] = A[M,K] @ B[N,K]^T + bias, f32 out
__global__ __launch_bounds__(256, 2) void gemm_o(
    const _Float16* __restrict__ A, const _Float16* __restrict__ B,
    const float* __restrict__ bias, float* __restrict__ C,
    int M, int N, int K) {
    GEMM_CORE(K)
    const int rowb = m0 + wr * 64 + (l >> 4) * 4;
    const int colb = n0 + wc * 64 + col16;
    float bv[4];
    #pragma unroll
    for (int n = 0; n < 4; ++n) bv[n] = bias[colb + n * 16];
    #pragma unroll
    for (int m = 0; m < 4; ++m)
        #pragma unroll
        for (int j = 0; j < 4; ++j) {
            float* crow = C + (size_t)(rowb + m * 16 + j) * N + colb;
            #pragma unroll
            for (int n = 0; n < 4; ++n) crow[n * 16] = acc[m][n][j] + bv[n];
        }
}

// QKV GEMM, fused epilogue -> Qf (scaled 0.125*log2e) / Kf [bh][s][64], VfT [bh][d][s]
#define QSCALE 0.18033688f
__global__ __launch_bounds__(256, 2) void gemm_qkv(
    const _Float16* __restrict__ A, const _Float16* __restrict__ B,
    const float* __restrict__ bias,
    _Float16* __restrict__ Qf, _Float16* __restrict__ Kf,
    _Float16* __restrict__ VfT, int K) {
    GEMM_CORE(K)
    const int rowb = m0 + wr * 64 + (l >> 4) * 4;
    const int colb = n0 + wc * 64 + col16;
    #pragma unroll
    for (int n = 0; n < 4; ++n) {
        int col = colb + n * 16;
        int h = col / 192;
        int rem = col - h * 192;
        int part = rem >> 6, d = rem & 63;   // wave-uniform
        float bv = bias[col];
        #pragma unroll
        for (int m = 0; m < 4; ++m) {
            int r0 = rowb + m * 16;
            int b = r0 >> 11, s0r = r0 & 2047;
            int bh = b * 16 + h;
            if (part == 0) {
                #pragma unroll
                for (int j = 0; j < 4; ++j)
                    Qf[((size_t)bh * 2048 + s0r + j) * 64 + d] =
                        (_Float16)((acc[m][n][j] + bv) * QSCALE);
            } else if (part == 1) {
                #pragma unroll
                for (int j = 0; j < 4; ++j)
                    Kf[((size_t)bh * 2048 + s0r + j) * 64 + d] = (_Float16)(acc[m][n][j] + bv);
            } else {
                half4 pk;
                pk[0] = (_Float16)(acc[m][n][0] + bv);
                pk[1] = (_Float16)(acc[m][n][1] + bv);
                pk[2] = (_Float16)(acc[m][n][2] + bv);
                pk[3] = (_Float16)(acc[m][n][3] + bv);
                *(half4*)&VfT[((size_t)bh * 64 + d) * 2048 + s0r] = pk;
            }
        }
    }
}

// MFMA flash attention, 32x32 f16, in-register P, absolute-score softmax with
// rsum-overflow guard (repair path ~never fires on sane data but is exact).
__global__ __launch_bounds__(256, 2) void mfma_attn(
    const _Float16* __restrict__ Qf, const _Float16* __restrict__ Kf,
    const _Float16* __restrict__ VfT, _Float16* __restrict__ vals) {
    __shared__ __align__(1024) unsigned char smem[32768];
    const int tid = threadIdx.x;
    const int l = tid & 63, w = tid >> 6;
    const int l31 = l & 31, hl = l >> 5;
    const int bh = blockIdx.y, q0 = blockIdx.x * 128;
    const int h = bh & 15, b = bh >> 4;

    half8 qf[4];
    {
        const _Float16* qp = Qf + ((size_t)bh * 2048 + q0 + w * 32 + l31) * 64 + hl * 8;
        #pragma unroll
        for (int c = 0; c < 4; ++c) qf[c] = *(const half8*)(qp + c * 16);
    }
    f32x16 zvec = {};          // persistent zero C-operand (no per-tile movs)
    f32x16 o0 = {}, o1 = {};   // O^T[d][q]
    float mshift = 0.f, lsum = 0.f;   // lsum is PER-LANE (own 32 keys/tile); combined at end

    const _Float16* Kg = Kf + (size_t)bh * 2048 * 64;
    const _Float16* Vg = VfT + (size_t)bh * 64 * 2048;

    int offK[2], offV[2];
    #pragma unroll
    for (int i = 0; i < 2; ++i) {
        int row2 = w * 8 + i * 4 + (l >> 4);
        int slot = (l & 15) ^ (row2 & 15);
        int row = row2 * 2 + (slot >> 3);
        int chunk = slot & 7;
        offK[i] = row * 64 + chunk * 8;
        offV[i] = row * 2048 + chunk * 8;
    }
    const int sbase = (l31 & 1) * 8;
    const int xr = (l31 >> 1) & 15;
    const int rb0 = (l31 >> 1) * 256;

    #define STAGE(kt0, buf)                                                            \
        {                                                                              \
            unsigned char* bK = smem + (buf) * 8192 + w * 2048;                        \
            unsigned char* bV = smem + 16384 + (buf) * 8192 + w * 2048;                \
            load_lds16(Kg + (size_t)(kt0) * 64 + offK[0], bK);                         \
            load_lds16(Kg + (size_t)(kt0) * 64 + offK[1], bK + 1024);                  \
            load_lds16(Vg + (kt0) + offV[0], bV);                                      \
            load_lds16(Vg + (kt0) + offV[1], bV + 1024);                               \
        }

    STAGE(0, 0)
    __syncthreads();
    int cur = 0;
    for (int t = 0; t < 32; ++t) {
        if (t + 1 < 32) STAGE((t + 1) * 64, cur ^ 1)
        const unsigned char* Ksb = smem + cur * 8192;
        const unsigned char* Vsb = smem + 16384 + cur * 8192;

        // ---- S^T = K @ Q^T (absolute scores, C chained off persistent zero) ----
        f32x16 s0_, s1_;
        __builtin_amdgcn_s_setprio(1);
        {
            int chOff = ((sbase + hl) ^ xr) << 4;
            half8 k0 = *(const half8*)(Ksb + rb0 + chOff);
            half8 k1 = *(const half8*)(Ksb + rb0 + 4096 + chOff);
            s0_ = __builtin_amdgcn_mfma_f32_32x32x16_f16(k0, qf[0], zvec, 0, 0, 0);
            s1_ = __builtin_amdgcn_mfma_f32_32x32x16_f16(k1, qf[0], zvec, 0, 0, 0);
        }
        #pragma unroll
        for (int kc = 1; kc < 4; ++kc) {
            int chOff = ((sbase + kc * 2 + hl) ^ xr) << 4;
            half8 k0 = *(const half8*)(Ksb + rb0 + chOff);
            half8 k1 = *(const half8*)(Ksb + rb0 + 4096 + chOff);
            s0_ = __builtin_amdgcn_mfma_f32_32x32x16_f16(k0, qf[kc], s0_, 0, 0, 0);
            s1_ = __builtin_amdgcn_mfma_f32_32x32x16_f16(k1, qf[kc], s1_, 0, 0, 0);
        }
        __builtin_amdgcn_s_setprio(0);

        // ---- shift only if a repair ever fired (never, typically) ----
        if (__any(mshift != 0.f)) {
            #pragma unroll
            for (int r = 0; r < 16; ++r) { s0_[r] -= mshift; s1_[r] -= mshift; }
        }

        // ---- exp2 + pack + per-lane row-sum (4 independent chains) ----
        float r0 = 0.f, r1 = 0.f, r2 = 0.f, r3 = 0.f;
        unsigned int a[2][8];
        #pragma unroll
        for (int j = 0; j < 8; ++j) {
            float p0 = __builtin_amdgcn_exp2f(s0_[2 * j]);
            float p1 = __builtin_amdgcn_exp2f(s0_[2 * j + 1]);
            float q0_ = __builtin_amdgcn_exp2f(s1_[2 * j]);
            float q1_ = __builtin_amdgcn_exp2f(s1_[2 * j + 1]);
            r0 += p0; r1 += p1; r2 += q0_; r3 += q1_;
            a[0][j] = __builtin_bit_cast(unsigned int, __builtin_amdgcn_cvt_pkrtz(p0, p1));
            a[1][j] = __builtin_bit_cast(unsigned int, __builtin_amdgcn_cvt_pkrtz(q0_, q1_));
        }
        float rsum = (r0 + r1) + (r2 + r3);

        // ---- overflow guard: p_max <= rsum, keep p within f16-safe 2^15 ----
        if (__any(rsum > 32768.f)) {   // repair (rare): establish a proper shift
            float pmax = s0_[0];
            #pragma unroll
            for (int r = 1; r < 16; ++r) pmax = fmaxf(pmax, s0_[r]);
            #pragma unroll
            for (int r = 0; r < 16; ++r) pmax = fmaxf(pmax, s1_[r]);
            pmax = fmaxf(pmax, __shfl_xor(pmax, 32, 64));
            float d_ = fmaxf(pmax, 0.f);
            float corr = __builtin_amdgcn_exp2f(-d_);
            #pragma unroll
            for (int r = 0; r < 16; ++r) { s0_[r] -= d_; s1_[r] -= d_; }
            #pragma unroll
            for (int r = 0; r < 16; ++r) { o0[r] *= corr; o1[r] *= corr; }
            lsum *= corr;
            mshift += d_;
            r0 = r1 = r2 = r3 = 0.f;
            #pragma unroll
            for (int j = 0; j < 8; ++j) {
                float p0 = __builtin_amdgcn_exp2f(s0_[2 * j]);
                float p1 = __builtin_amdgcn_exp2f(s0_[2 * j + 1]);
                float q0_ = __builtin_amdgcn_exp2f(s1_[2 * j]);
                float q1_ = __builtin_amdgcn_exp2f(s1_[2 * j + 1]);
                r0 += p0; r1 += p1; r2 += q0_; r3 += q1_;
                a[0][j] = __builtin_bit_cast(unsigned int, __builtin_amdgcn_cvt_pkrtz(p0, p1));
                a[1][j] = __builtin_bit_cast(unsigned int, __builtin_amdgcn_cvt_pkrtz(q0_, q1_));
            }
            rsum = (r0 + r1) + (r2 + r3);
        }
        lsum += rsum;

        // ---- P^T B-fragments in-register ----
        #pragma unroll
        for (int c = 0; c < 2; ++c) {
            pl32swap(a[c][0], a[c][2]);
            pl32swap(a[c][1], a[c][3]);
            pl32swap(a[c][4], a[c][6]);
            pl32swap(a[c][5], a[c][7]);
        }

        // ---- O^T += V^T @ P^T ----
        __builtin_amdgcn_s_setprio(1);
        #pragma unroll
        for (int kk = 0; kk < 4; ++kk) {
            u32x4 pw;
            pw.x = a[kk >> 1][(kk & 1) * 4 + 0];
            pw.y = a[kk >> 1][(kk & 1) * 4 + 1];
            pw.z = a[kk >> 1][(kk & 1) * 4 + 2];
            pw.w = a[kk >> 1][(kk & 1) * 4 + 3];
            half8 pf = __builtin_bit_cast(half8, pw);
            int chOff = ((sbase + kk * 2 + hl) ^ xr) << 4;
            half8 v0 = *(const half8*)(Vsb + rb0 + chOff);
            half8 v1 = *(const half8*)(Vsb + rb0 + 4096 + chOff);
            o0 = __builtin_amdgcn_mfma_f32_32x32x16_f16(v0, pf, o0, 0, 0, 0);
            o1 = __builtin_amdgcn_mfma_f32_32x32x16_f16(v1, pf, o1, 0, 0, 0);
        }
        __builtin_amdgcn_s_setprio(0);
        __syncthreads();
        cur ^= 1;
    }

    // ---- epilogue: combine half-wave lsums once, then write f16 ----
    lsum += __shfl_xor(lsum, 32, 64);
    float inv = 1.f / lsum;
    size_t orow = ((size_t)(b * 2048 + q0 + w * 32 + l31)) * 1024 + h * 64;
    #pragma unroll
    for (int dc = 0; dc < 2; ++dc) {
        const f32x16* op = dc ? &o1 : &o0;
        #pragma unroll
        for (int rq = 0; rq < 4; ++rq) {
            int d0 = dc * 32 + rq * 8 + hl * 4;
            half4 hv;
            #pragma unroll
            for (int j = 0; j < 4; ++j) hv[j] = (_Float16)((*op)[rq * 4 + j] * inv);
            *(half4*)(vals + orow + d0) = hv;
        }
    }
}

extern "C" void kernel_launch(void* const* d_in, const int* in_sizes, int n_in,
                              void* d_out, int out_size, void* d_ws, size_t ws_size,
                              hipStream_t stream) {
    const float* x     = (const float*)d_in[0];
    const float* w_qkv = (const float*)d_in[1];
    const float* b_qkv = (const float*)d_in[2];
    const float* w_o   = (const float*)d_in[3];
    const float* b_o   = (const float*)d_in[4];
    float* out = (float*)d_out;

    const int B = 2, S = 2048, D = 1024;
    const int M = B * S;          // 4096
    const int N1 = 3 * D;         // 3072
    const int BH = B * NHEADS;    // 32

    _Float16* xf  = (_Float16*)d_ws;                  // [4096,1024]
    _Float16* wqf = xf  + (size_t)M * D;              // [3072,1024]
    _Float16* wof = wqf + (size_t)N1 * D;             // [1024,1024]
    _Float16* Qf  = wof + (size_t)D * D;              // [32,2048,64]
    _Float16* Kf  = Qf  + (size_t)BH * S * HD;
    _Float16* VfT = Kf  + (size_t)BH * S * HD;        // [32,64,2048]
    _Float16* vals = xf;   // reuse x-f16 space after gemm_qkv

    // 0) all f32->f16 conversions in one launch
    cvt_all<<<(NX + NWQ + NWO) / 2048, 256, 0, stream>>>(x, w_qkv, w_o, xf, wqf, wof);

    // 1) fused QKV projection -> f16 attention layouts
    gemm_qkv<<<dim3(N1 / 128, M / 128), 256, 0, stream>>>(xf, wqf, b_qkv, Qf, Kf, VfT, D);

    // 2) MFMA flash attention (32x32 f16, in-register P)
    mfma_attn<<<dim3(S / 128, BH), 256, 0, stream>>>(Qf, Kf, VfT, vals);

    // 3) out = vals @ w_o^T + b_o
    gemm_o<<<dim3(D / 128, M / 128), 256, 0, stream>>>(vals, wof, b_o, out, M, D, D);
}